// Round 8
// baseline (1083.557 us; speedup 1.0000x reference)
//
#include <hip/hip_runtime.h>
#include <hip/hip_bf16.h>
#include <stdint.h>
#include <math.h>

#define NROWS  8192
#define DIM    768                        // elements per row (1 B each in fp8)
#define BK     128                        // K per tile (fp8 bytes) = MFMA K
#define NKT    (DIM / BK)                 // 6 K-tiles -> 3 iterations x 2 tiles
#define BM     256
#define NTILE2 32                         // 8192/256
#define EPSV   1e-6f
#define NJN    (NTILE2 * NTILE2)           // 1024 X-vs-Y tiles
#define NJJ    (NTILE2 * (NTILE2 + 1) / 2) // 528 upper-tri X-vs-X tiles
#define NBLK   (NJN + NJJ)                 // 1552 = 8 * 194 (XCD-divisible)

typedef __attribute__((ext_vector_type(4))) int   int4v;
typedef __attribute__((ext_vector_type(8))) int   int8v;
typedef __attribute__((ext_vector_type(4))) float f32x4;
typedef unsigned char uchar;

// async global->LDS, 16B per lane; LDS dest is wave-uniform base (+lane*16 by HW)
__device__ __forceinline__ void gload16(const void* g, void* l) {
    __builtin_amdgcn_global_load_lds(
        (const __attribute__((address_space(1))) void*)g,
        (__attribute__((address_space(3))) void*)l,
        16, 0, 0);
}

// ------- prep: fp8-e4m3 convert into Z=[X;Y], folded row stats (exact fp32) -------
__global__ __launch_bounds__(256)
void prep(const float* __restrict__ X, const float* __restrict__ Y,
          float* __restrict__ SXa, float* __restrict__ TB,
          uchar* __restrict__ Zf8) {
    int row = blockIdx.x;                  // 0..16383
    bool isX = row < NROWS;
    const float* p = (isX ? X : Y) + (size_t)(isX ? row : row - NROWS) * DIM;
    uint32_t* q = (uint32_t*)(Zf8 + (size_t)row * DIM);
    int t = threadIdx.x;
    float s = 0.f, qs = 0.f;
    if (t < 192) {                         // 192 * 4 = 768 elems
        float4 v = *(const float4*)(p + 4 * t);
        uint32_t u = __builtin_amdgcn_cvt_pk_fp8_f32(v.x, v.y, 0u, false);
        u = __builtin_amdgcn_cvt_pk_fp8_f32(v.z, v.w, u, true);
        q[t] = u;
        s  = v.x + v.y + v.z + v.w;
        qs = v.x*v.x + v.y*v.y + v.z*v.z + v.w*v.w;
    }
    #pragma unroll
    for (int o = 32; o; o >>= 1) { s += __shfl_down(s, o); qs += __shfl_down(qs, o); }
    __shared__ float sh[8];
    int wave = t >> 6, lane = t & 63;
    if (lane == 0) { sh[wave] = s; sh[4 + wave] = qs; }
    __syncthreads();
    if (t == 0) {
        float ss = sh[0]+sh[1]+sh[2]+sh[3];
        float qq = sh[4]+sh[5]+sh[6]+sh[7];
        if (isX) SXa[row] = qq + 2.f*EPSV*ss;
        TB[row] = qq - 2.f*EPSV*ss + (float)DIM*EPSV*EPSV;
    }
}

// ------- fused MX-fp8 GEMM, 256x256, 8 waves, 8-phase pipelined (m201-style) ------
// LDS swizzle (both-sides involution, verified r5-r7): LDS[row][c] holds global
// element col c^((row&7)<<4); linear gload_lds dest + pre-swizzled global source;
// ds_read applies the same XOR.
// Phase = one C-quadrant (mh,nh) x full K=128 of one K-tile; 8 MFMA + 12 ds_read.
// Stage units: A-half h = rows {q*128 + h*64 + [0,64)}, B-half h = rows
// {q*128 + wc*64 + h*32 + [0,32)}; each 16KB = 2 gload16/wave.
// Ledger (verified): quadrants ph1-4=(0,0),(0,1),(1,0),(1,1) on buf0 tile 2I;
// ph5-8 same on buf1 tile 2I+1. Stages: ph1: odd-tile(2I+1) A1+B1 -> buf1;
// ph3: A0(2I+2); ph4: B0(2I+2)+vmcnt(4); ph5: A1+B1(2I+2); ph7: A0(2I+3);
// ph8: B0(2I+3)+vmcnt(4). Every stage lands >=1 barrier after the last read of
// the region it overwrites; every read is covered by a vmcnt retiring its stage.
__global__ __launch_bounds__(512, 2)
void gemm_loss(const uchar* __restrict__ Z, const int* __restrict__ labels,
               const float* __restrict__ SXa, const float* __restrict__ TB,
               float4* __restrict__ partials) {
    // bijective XCD swizzle: 1552 = 8 * 194
    const int bid = (blockIdx.x & 7) * (NBLK / 8) + (blockIdx.x >> 3);
    const int t = threadIdx.x;

    int ti, tj, jrow0;                      // jrow0 = B-side row base in Z
    bool jj;
    if (bid < NJN) {
        jj = false; ti = bid >> 5; tj = bid & 31; jrow0 = NROWS + tj * BM;
    } else {
        jj = true;
        int u = bid - NJN;                  // 0..527, upper-tri (ti<=tj), 32 rows
        int t0 = (int)((65.0 - sqrt(65.0*65.0 - 8.0*(double)u)) * 0.5);
        if (t0 < 0) t0 = 0; if (t0 > 31) t0 = 31;
        while (t0 < 31 && (t0 + 1) * (65 - (t0 + 1)) / 2 <= u) ++t0;
        while (t0 > 0  && t0 * (65 - t0) / 2 > u) --t0;
        ti = t0; tj = ti + (u - ti * (65 - ti) / 2); jrow0 = tj * BM;
    }
    const int i0 = ti * BM;

    __shared__ __align__(16) uchar Asm[2][BM * BK];   // 32 KB per buf
    __shared__ __align__(16) uchar Bsm[2][BM * BK];
    __shared__ float red[8][4];

    const int wave = t >> 6, lane = t & 63;
    const int wr = wave >> 2;               // 0..1 (M half: 128 rows)
    const int wc = wave & 3;                // 0..3 (N quarter: 64 cols)

    // staging source: row&7 == lane>>3 always, so inverse-swizzled col is:
    const int cS = ((lane & 7) * 16) ^ ((lane >> 3) << 4);
    const int lB = (wave >> 2) * 64 + (wave & 3) * 8;     // B LDS row base/wave
    const uchar* pAs = Z + (size_t)(i0 + wave * 8 + (lane >> 3)) * DIM + cS;
    const uchar* pBs = Z + (size_t)(jrow0 + lB + (lane >> 3)) * DIM + cS;

    const int lrow = lane & 15;
    const int kg   = (lane >> 4) * 32;      // 32-byte K-group per lane quarter

    f32x4 acc[8][4] = {};

#define STAGE_A(d, h, kb)                                                      \
    do {                                                                       \
        gload16(pAs + (size_t)((h)*64)       * DIM + (kb),                     \
                &Asm[d][((h)*64 + wave*8) * 128]);                             \
        gload16(pAs + (size_t)(128 + (h)*64) * DIM + (kb),                     \
                &Asm[d][(128 + (h)*64 + wave*8) * 128]);                       \
    } while (0)

#define STAGE_B(d, h, kb)                                                      \
    do {                                                                       \
        gload16(pBs + (size_t)((h)*32)       * DIM + (kb),                     \
                &Bsm[d][(lB + (h)*32) * 128]);                                 \
        gload16(pBs + (size_t)(128 + (h)*32) * DIM + (kb),                     \
                &Bsm[d][(lB + 128 + (h)*32) * 128]);                           \
    } while (0)

#define FENCE() asm volatile("" ::: "memory")
#define BAR()   do { FENCE(); __builtin_amdgcn_s_barrier(); FENCE(); } while (0)
#define VMW4()  asm volatile("s_waitcnt vmcnt(4)" ::: "memory")
#define VMW0()  asm volatile("s_waitcnt vmcnt(0)" ::: "memory")

#define PHASE(d, mh, nh, STAGE_CODE, WAIT_CODE)                                \
    do {                                                                       \
        int8v bfr[2], afr[4];                                                  \
        _Pragma("unroll")                                                      \
        for (int ni = 0; ni < 2; ++ni) {                                       \
            int rr = wc*64 + ((nh)*2 + ni)*16 + lrow;                          \
            int sw = (rr & 7) << 4;                                            \
            int4v lo = *(const int4v*)&Bsm[d][rr*128 + (kg ^ sw)];             \
            int4v hi = *(const int4v*)&Bsm[d][rr*128 + ((kg + 16) ^ sw)];      \
            bfr[ni] = __builtin_shufflevector(lo, hi, 0,1,2,3,4,5,6,7);        \
        }                                                                      \
        _Pragma("unroll")                                                      \
        for (int mi = 0; mi < 4; ++mi) {                                       \
            int rr = wr*128 + ((mh)*4 + mi)*16 + lrow;                         \
            int sw = (rr & 7) << 4;                                            \
            int4v lo = *(const int4v*)&Asm[d][rr*128 + (kg ^ sw)];             \
            int4v hi = *(const int4v*)&Asm[d][rr*128 + ((kg + 16) ^ sw)];      \
            afr[mi] = __builtin_shufflevector(lo, hi, 0,1,2,3,4,5,6,7);        \
        }                                                                      \
        STAGE_CODE;                                                            \
        WAIT_CODE;                                                             \
        BAR();                                                                 \
        __builtin_amdgcn_s_setprio(1);                                         \
        _Pragma("unroll")                                                      \
        for (int mi = 0; mi < 4; ++mi)                                         \
            _Pragma("unroll")                                                  \
            for (int ni = 0; ni < 2; ++ni)                                     \
                acc[(mh)*4 + mi][(nh)*2 + ni] =                                \
                    __builtin_amdgcn_mfma_scale_f32_16x16x128_f8f6f4(          \
                        afr[mi], bfr[ni], acc[(mh)*4 + mi][(nh)*2 + ni],       \
                        0, 0, 0, 0x7F7F7F7Fu, 0, 0x7F7F7F7Fu);                 \
        __builtin_amdgcn_s_setprio(0);                                         \
        BAR();                                                                 \
    } while (0)

    // prologue: tile0 fully + tile1 A0,B0 (12 loads); vmcnt(4) -> tile0 ready
    STAGE_A(0, 0, 0); STAGE_B(0, 0, 0); STAGE_A(0, 1, 0); STAGE_B(0, 1, 0);
    STAGE_A(1, 0, BK); STAGE_B(1, 0, BK);
    VMW4();
    BAR();

    #pragma unroll 1
    for (int it = 0; it < 3; ++it) {
        const int k1 = (2*it + 1) * BK;
        const int k2 = (2*it + 2) * BK;
        const int k3 = (2*it + 3) * BK;
        const bool more = (it < 2);
        // tile 2I on buf0
        PHASE(0, 0, 0, { STAGE_A(1, 1, k1); STAGE_B(1, 1, k1); }, {});
        PHASE(0, 0, 1, {}, {});
        PHASE(0, 1, 0, { if (more) STAGE_A(0, 0, k2); }, {});
        PHASE(0, 1, 1, { if (more) STAGE_B(0, 0, k2); },
                       { if (more) VMW4(); else VMW0(); });
        // tile 2I+1 on buf1
        PHASE(1, 0, 0, { if (more) { STAGE_A(0, 1, k2); STAGE_B(0, 1, k2); } }, {});
        PHASE(1, 0, 1, {}, {});
        PHASE(1, 1, 0, { if (more) STAGE_A(1, 0, k3); }, {});
        PHASE(1, 1, 1, { if (more) STAGE_B(1, 0, k3); },
                       { if (more) VMW4(); else VMW0(); });
    }

    // -------- epilogue (C/D: col=lane&15, row=(lane>>4)*4+reg) --------
    const int il = wr*128 + ((lane >> 4) << 2);  // + mi*16 + r
    const int jl = wc*64 + (lane & 15);          // + ni*16

    float tbv[4];
    #pragma unroll
    for (int ni = 0; ni < 4; ++ni)
        tbv[ni] = TB[jrow0 + jl + ni*16];

    float pos = 0.f, neg = 0.f, cross = 0.f, cnt = 0.f;
    float mn = 1e30f;                        // min over valid neg/cross cands

    if (jj) {
        int labj[4];
        #pragma unroll
        for (int ni = 0; ni < 4; ++ni)
            labj[ni] = labels[tj * BM + jl + ni*16];
        const bool difftile = (ti != tj);
        #pragma unroll
        for (int mi = 0; mi < 8; ++mi) {
            float4 sx4 = *(const float4*)&SXa[i0 + il + mi*16];
            int4   la4 = *(const int4*)&labels[i0 + il + mi*16];
            float sxr[4] = {sx4.x, sx4.y, sx4.z, sx4.w};
            int   lar[4] = {la4.x, la4.y, la4.z, la4.w};
            #pragma unroll
            for (int ni = 0; ni < 4; ++ni)
                #pragma unroll
                for (int r = 0; r < 4; ++r) {
                    float d2 = __builtin_fmaf(-2.f, acc[mi][ni][r],
                                              sxr[r] + tbv[ni]);
                    bool lt   = difftile | ((il + mi*16 + r) < (jl + ni*16));
                    bool same = (lar[r] == labj[ni]);
                    if (lt & same) { pos += fmaxf(d2, 0.f); cnt += 1.f; }
                    mn = fminf(mn, (lt & !same) ? d2 : 1e30f);
                }
        }
    } else {
        #pragma unroll
        for (int mi = 0; mi < 8; ++mi) {
            float4 sx4 = *(const float4*)&SXa[i0 + il + mi*16];
            float sxr[4] = {sx4.x, sx4.y, sx4.z, sx4.w};
            #pragma unroll
            for (int ni = 0; ni < 4; ++ni)
                #pragma unroll
                for (int r = 0; r < 4; ++r) {
                    float d2 = __builtin_fmaf(-2.f, acc[mi][ni][r],
                                              sxr[r] + tbv[ni]);
                    mn = fminf(mn, d2);
                }
        }
    }

    // rare exact path: only if some margin-active pair exists (never on this data)
    if (__any(mn < 1.f)) {
        int labj[4] = {0,0,0,0};
        if (jj)
            #pragma unroll
            for (int ni = 0; ni < 4; ++ni)
                labj[ni] = labels[tj * BM + jl + ni*16];
        const bool difftile = (ti != tj);
        #pragma unroll
        for (int mi = 0; mi < 8; ++mi) {
            float4 sx4 = *(const float4*)&SXa[i0 + il + mi*16];
            float sxr[4] = {sx4.x, sx4.y, sx4.z, sx4.w};
            int lar[4] = {0,0,0,0};
            if (jj) {
                int4 la4 = *(const int4*)&labels[i0 + il + mi*16];
                lar[0]=la4.x; lar[1]=la4.y; lar[2]=la4.z; lar[3]=la4.w;
            }
            #pragma unroll
            for (int ni = 0; ni < 4; ++ni)
                #pragma unroll
                for (int r = 0; r < 4; ++r) {
                    float d2 = __builtin_fmaf(-2.f, acc[mi][ni][r],
                                              sxr[r] + tbv[ni]);
                    d2 = fmaxf(d2, 0.f);
                    float dist = sqrtf(fmaxf(d2, 1e-12f));
                    float m = fmaxf(1.f - dist, 0.f);
                    float s2 = m * m;
                    if (jj) {
                        bool lt   = difftile | ((il + mi*16 + r) < (jl + ni*16));
                        bool same = (lar[r] == labj[ni]);
                        if (lt & !same) neg += s2;
                    } else {
                        cross += s2;
                    }
                }
        }
    }

    #pragma unroll
    for (int o = 32; o; o >>= 1) {
        pos   += __shfl_down(pos, o);
        neg   += __shfl_down(neg, o);
        cross += __shfl_down(cross, o);
        cnt   += __shfl_down(cnt, o);
    }
    if (lane == 0) { red[wave][0] = pos; red[wave][1] = neg;
                     red[wave][2] = cross; red[wave][3] = cnt; }
    __syncthreads();
    if (t == 0) {
        float4 v = {0.f, 0.f, 0.f, 0.f};
        #pragma unroll
        for (int w = 0; w < 8; ++w) {
            v.x += red[w][0]; v.y += red[w][1];
            v.z += red[w][2]; v.w += red[w][3];
        }
        partials[bid] = v;
    }
#undef STAGE_A
#undef STAGE_B
#undef PHASE
#undef FENCE
#undef BAR
#undef VMW4
#undef VMW0
}

// ---------------- final reduce ----------------
__global__ __launch_bounds__(256)
void finalize_kernel(const float4* __restrict__ partials, float* __restrict__ out) {
    int t = threadIdx.x;
    double p = 0, n = 0, c = 0, k = 0;
    for (int s = t; s < NBLK; s += 256) {
        float4 v = partials[s];
        p += v.x; n += v.y; c += v.z; k += v.w;
    }
    __shared__ double sh[256][4];
    sh[t][0] = p; sh[t][1] = n; sh[t][2] = c; sh[t][3] = k;
    __syncthreads();
    for (int o = 128; o; o >>= 1) {
        if (t < o) {
            sh[t][0] += sh[t+o][0]; sh[t][1] += sh[t+o][1];
            sh[t][2] += sh[t+o][2]; sh[t][3] += sh[t+o][3];
        }
        __syncthreads();
    }
    if (t == 0) {
        double npos = sh[0][3] < 1.0 ? 1.0 : sh[0][3];
        double total = (double)NROWS * (NROWS - 1) * 0.5;
        double nneg = total - sh[0][3]; if (nneg < 1.0) nneg = 1.0;
        double loss = sh[0][0] / npos + sh[0][1] / nneg
                    + sh[0][2] / ((double)NROWS * (double)NROWS);
        out[0] = (float)loss;
    }
}

extern "C" void kernel_launch(void* const* d_in, const int* in_sizes, int n_in,
                              void* d_out, int out_size, void* d_ws, size_t ws_size,
                              hipStream_t stream) {
    const float* X      = (const float*)d_in[0];
    const float* Y      = (const float*)d_in[1];
    const int*   labels = (const int*)d_in[2];
    float* out = (float*)d_out;
    char*  ws  = (char*)d_ws;

    // ws: partials (128KB) | SXa (32KB) | TB (64KB) | Zf8 (16384*768 = 12.6MB)
    float4* partials = (float4*)ws;
    float*  SXa      = (float*)(ws + 128*1024);
    float*  TB       = (float*)(ws + 128*1024 + 32*1024);
    uchar*  Zf8      = (uchar*)(ws + 256*1024);

    prep<<<2 * NROWS, 256, 0, stream>>>(X, Y, SXa, TB, Zf8);
    gemm_loss<<<NBLK, 512, 0, stream>>>(Zf8, labels, SXa, TB, partials);
    finalize_kernel<<<1, 256, 0, stream>>>(partials, out);
}

// Round 9
// 1032.584 us; speedup vs baseline: 1.0494x; 1.0494x over previous
//
#include <hip/hip_runtime.h>
#include <hip/hip_bf16.h>
#include <stdint.h>
#include <math.h>

#define NROWS  8192
#define DIM    768                        // elements per row (1 B each in fp8)
#define BK     128                        // K per tile (fp8 bytes) = MFMA K
#define NKT    (DIM / BK)                 // 6 K-tiles -> 3 iterations x 2 tiles
#define BM     256
#define NTILE2 32                         // 8192/256
#define EPSV   1e-6f
#define NJN    (NTILE2 * NTILE2)           // 1024 X-vs-Y tiles
#define NJJ    (NTILE2 * (NTILE2 + 1) / 2) // 528 upper-tri X-vs-X tiles
#define NBLK   (NJN + NJJ)                 // 1552 = 8 * 194 (XCD-divisible)

typedef __attribute__((ext_vector_type(4))) int   int4v;
typedef __attribute__((ext_vector_type(8))) int   int8v;
typedef __attribute__((ext_vector_type(4))) float f32x4;
typedef unsigned char uchar;

// async global->LDS, 16B per lane; LDS dest is wave-uniform base (+lane*16 by HW)
__device__ __forceinline__ void gload16(const void* g, void* l) {
    __builtin_amdgcn_global_load_lds(
        (const __attribute__((address_space(1))) void*)g,
        (__attribute__((address_space(3))) void*)l,
        16, 0, 0);
}

// ------- prep: fp8-e4m3 convert into Z=[X;Y], folded row stats (exact fp32) -------
__global__ __launch_bounds__(256)
void prep(const float* __restrict__ X, const float* __restrict__ Y,
          float* __restrict__ SXa, float* __restrict__ TB,
          uchar* __restrict__ Zf8) {
    int row = blockIdx.x;                  // 0..16383
    bool isX = row < NROWS;
    const float* p = (isX ? X : Y) + (size_t)(isX ? row : row - NROWS) * DIM;
    uint32_t* q = (uint32_t*)(Zf8 + (size_t)row * DIM);
    int t = threadIdx.x;
    float s = 0.f, qs = 0.f;
    if (t < 192) {                         // 192 * 4 = 768 elems
        float4 v = *(const float4*)(p + 4 * t);
        uint32_t u = __builtin_amdgcn_cvt_pk_fp8_f32(v.x, v.y, 0u, false);
        u = __builtin_amdgcn_cvt_pk_fp8_f32(v.z, v.w, u, true);
        q[t] = u;
        s  = v.x + v.y + v.z + v.w;
        qs = v.x*v.x + v.y*v.y + v.z*v.z + v.w*v.w;
    }
    #pragma unroll
    for (int o = 32; o; o >>= 1) { s += __shfl_down(s, o); qs += __shfl_down(qs, o); }
    __shared__ float sh[8];
    int wave = t >> 6, lane = t & 63;
    if (lane == 0) { sh[wave] = s; sh[4 + wave] = qs; }
    __syncthreads();
    if (t == 0) {
        float ss = sh[0]+sh[1]+sh[2]+sh[3];
        float qq = sh[4]+sh[5]+sh[6]+sh[7];
        if (isX) SXa[row] = qq + 2.f*EPSV*ss;
        TB[row] = qq - 2.f*EPSV*ss + (float)DIM*EPSV*EPSV;
    }
}

// ------- fused MX-fp8 GEMM, 256x256, 8 waves, 8-phase pipelined (m201-style) ------
// LDS swizzle (both-sides involution, verified r5-r8): LDS[row][c] holds global
// element col c^((row&7)<<4); linear gload_lds dest + pre-swizzled global source;
// ds_read applies the same XOR.
// Phase = one C-quadrant (mh,nh) x full K=128 of one K-tile; 8 MFMA + 12 ds_read.
// Ledger (verified r8, absmax 0): quadrants ph1-4=(0,0),(0,1),(1,0),(1,1) on buf0
// tile 2I; ph5-8 same on buf1 tile 2I+1. Stages: ph1: tile(2I+1) A1+B1 -> buf1;
// ph3: A0(2I+2); ph4: B0(2I+2)+vmcnt(4); ph5: A1+B1(2I+2); ph7: A0(2I+3);
// ph8: B0(2I+3)+vmcnt(4). Every stage lands >=1 barrier after the last read of
// the region it overwrites; every read is covered by a vmcnt retiring its stage.
// NOTE __launch_bounds__(512, 1): LDS (128KB) caps at 1 block/CU anyway; the
// r8 (512,2) variant capped VGPRs at 128 -> catastrophic scratch spill
// (WRITE_SIZE 2.7GB). minwaves=1 restores the full register budget.
__global__ __launch_bounds__(512, 1)
void gemm_loss(const uchar* __restrict__ Z, const int* __restrict__ labels,
               const float* __restrict__ SXa, const float* __restrict__ TB,
               float4* __restrict__ partials) {
    // bijective XCD swizzle: 1552 = 8 * 194
    const int bid = (blockIdx.x & 7) * (NBLK / 8) + (blockIdx.x >> 3);
    const int t = threadIdx.x;

    int ti, tj, jrow0;                      // jrow0 = B-side row base in Z
    bool jj;
    if (bid < NJN) {
        jj = false; ti = bid >> 5; tj = bid & 31; jrow0 = NROWS + tj * BM;
    } else {
        jj = true;
        int u = bid - NJN;                  // 0..527, upper-tri (ti<=tj), 32 rows
        int t0 = (int)((65.0 - sqrt(65.0*65.0 - 8.0*(double)u)) * 0.5);
        if (t0 < 0) t0 = 0; if (t0 > 31) t0 = 31;
        while (t0 < 31 && (t0 + 1) * (65 - (t0 + 1)) / 2 <= u) ++t0;
        while (t0 > 0  && t0 * (65 - t0) / 2 > u) --t0;
        ti = t0; tj = ti + (u - ti * (65 - ti) / 2); jrow0 = tj * BM;
    }
    const int i0 = ti * BM;

    __shared__ __align__(16) uchar Asm[2][BM * BK];   // 32 KB per buf
    __shared__ __align__(16) uchar Bsm[2][BM * BK];
    __shared__ float red[8][4];

    const int wave = t >> 6, lane = t & 63;
    const int wr = wave >> 2;               // 0..1 (M half: 128 rows)
    const int wc = wave & 3;                // 0..3 (N quarter: 64 cols)

    // staging source: row&7 == lane>>3 always, so inverse-swizzled col is:
    const int cS = ((lane & 7) * 16) ^ ((lane >> 3) << 4);
    const int lB = (wave >> 2) * 64 + (wave & 3) * 8;     // B LDS row base/wave
    const uchar* pAs = Z + (size_t)(i0 + wave * 8 + (lane >> 3)) * DIM + cS;
    const uchar* pBs = Z + (size_t)(jrow0 + lB + (lane >> 3)) * DIM + cS;

    const int lrow = lane & 15;
    const int kg   = (lane >> 4) * 32;      // 32-byte K-group per lane quarter

    f32x4 acc[8][4] = {};

#define STAGE_A(d, h, kb)                                                      \
    do {                                                                       \
        gload16(pAs + (size_t)((h)*64)       * DIM + (kb),                     \
                &Asm[d][((h)*64 + wave*8) * 128]);                             \
        gload16(pAs + (size_t)(128 + (h)*64) * DIM + (kb),                     \
                &Asm[d][(128 + (h)*64 + wave*8) * 128]);                       \
    } while (0)

#define STAGE_B(d, h, kb)                                                      \
    do {                                                                       \
        gload16(pBs + (size_t)((h)*32)       * DIM + (kb),                     \
                &Bsm[d][(lB + (h)*32) * 128]);                                 \
        gload16(pBs + (size_t)(128 + (h)*32) * DIM + (kb),                     \
                &Bsm[d][(lB + 128 + (h)*32) * 128]);                           \
    } while (0)

#define FENCE() asm volatile("" ::: "memory")
#define BAR()   do { FENCE(); __builtin_amdgcn_s_barrier(); FENCE(); } while (0)
#define VMW4()  asm volatile("s_waitcnt vmcnt(4)" ::: "memory")
#define VMW0()  asm volatile("s_waitcnt vmcnt(0)" ::: "memory")

#define PHASE(d, mh, nh, STAGE_CODE, WAIT_CODE)                                \
    do {                                                                       \
        int8v bfr[2], afr[4];                                                  \
        _Pragma("unroll")                                                      \
        for (int ni = 0; ni < 2; ++ni) {                                       \
            int rr = wc*64 + ((nh)*2 + ni)*16 + lrow;                          \
            int sw = (rr & 7) << 4;                                            \
            int4v lo = *(const int4v*)&Bsm[d][rr*128 + (kg ^ sw)];             \
            int4v hi = *(const int4v*)&Bsm[d][rr*128 + ((kg + 16) ^ sw)];      \
            bfr[ni] = __builtin_shufflevector(lo, hi, 0,1,2,3,4,5,6,7);        \
        }                                                                      \
        _Pragma("unroll")                                                      \
        for (int mi = 0; mi < 4; ++mi) {                                       \
            int rr = wr*128 + ((mh)*4 + mi)*16 + lrow;                         \
            int sw = (rr & 7) << 4;                                            \
            int4v lo = *(const int4v*)&Asm[d][rr*128 + (kg ^ sw)];             \
            int4v hi = *(const int4v*)&Asm[d][rr*128 + ((kg + 16) ^ sw)];      \
            afr[mi] = __builtin_shufflevector(lo, hi, 0,1,2,3,4,5,6,7);        \
        }                                                                      \
        STAGE_CODE;                                                            \
        WAIT_CODE;                                                             \
        BAR();                                                                 \
        __builtin_amdgcn_s_setprio(1);                                         \
        _Pragma("unroll")                                                      \
        for (int mi = 0; mi < 4; ++mi)                                         \
            _Pragma("unroll")                                                  \
            for (int ni = 0; ni < 2; ++ni)                                     \
                acc[(mh)*4 + mi][(nh)*2 + ni] =                                \
                    __builtin_amdgcn_mfma_scale_f32_16x16x128_f8f6f4(          \
                        afr[mi], bfr[ni], acc[(mh)*4 + mi][(nh)*2 + ni],       \
                        0, 0, 0, 0x7F7F7F7Fu, 0, 0x7F7F7F7Fu);                 \
        __builtin_amdgcn_s_setprio(0);                                         \
        BAR();                                                                 \
    } while (0)

    // prologue: tile0 fully + tile1 A0,B0 (12 loads); vmcnt(4) -> tile0 ready
    STAGE_A(0, 0, 0); STAGE_B(0, 0, 0); STAGE_A(0, 1, 0); STAGE_B(0, 1, 0);
    STAGE_A(1, 0, BK); STAGE_B(1, 0, BK);
    VMW4();
    BAR();

    #pragma unroll 1
    for (int it = 0; it < 3; ++it) {
        const int k1 = (2*it + 1) * BK;
        const int k2 = (2*it + 2) * BK;
        const int k3 = (2*it + 3) * BK;
        const bool more = (it < 2);
        // tile 2I on buf0
        PHASE(0, 0, 0, { STAGE_A(1, 1, k1); STAGE_B(1, 1, k1); }, {});
        PHASE(0, 0, 1, {}, {});
        PHASE(0, 1, 0, { if (more) STAGE_A(0, 0, k2); }, {});
        PHASE(0, 1, 1, { if (more) STAGE_B(0, 0, k2); },
                       { if (more) VMW4(); else VMW0(); });
        // tile 2I+1 on buf1
        PHASE(1, 0, 0, { if (more) { STAGE_A(0, 1, k2); STAGE_B(0, 1, k2); } }, {});
        PHASE(1, 0, 1, {}, {});
        PHASE(1, 1, 0, { if (more) STAGE_A(1, 0, k3); }, {});
        PHASE(1, 1, 1, { if (more) STAGE_B(1, 0, k3); },
                       { if (more) VMW4(); else VMW0(); });
    }

    // -------- epilogue (C/D: col=lane&15, row=(lane>>4)*4+reg) --------
    const int il = wr*128 + ((lane >> 4) << 2);  // + mi*16 + r
    const int jl = wc*64 + (lane & 15);          // + ni*16

    float tbv[4];
    #pragma unroll
    for (int ni = 0; ni < 4; ++ni)
        tbv[ni] = TB[jrow0 + jl + ni*16];

    float pos = 0.f, neg = 0.f, cross = 0.f, cnt = 0.f;
    float mn = 1e30f;                        // min over valid neg/cross cands

    if (jj) {
        int labj[4];
        #pragma unroll
        for (int ni = 0; ni < 4; ++ni)
            labj[ni] = labels[tj * BM + jl + ni*16];
        const bool difftile = (ti != tj);
        #pragma unroll
        for (int mi = 0; mi < 8; ++mi) {
            float4 sx4 = *(const float4*)&SXa[i0 + il + mi*16];
            int4   la4 = *(const int4*)&labels[i0 + il + mi*16];
            float sxr[4] = {sx4.x, sx4.y, sx4.z, sx4.w};
            int   lar[4] = {la4.x, la4.y, la4.z, la4.w};
            #pragma unroll
            for (int ni = 0; ni < 4; ++ni)
                #pragma unroll
                for (int r = 0; r < 4; ++r) {
                    float d2 = __builtin_fmaf(-2.f, acc[mi][ni][r],
                                              sxr[r] + tbv[ni]);
                    bool lt   = difftile | ((il + mi*16 + r) < (jl + ni*16));
                    bool same = (lar[r] == labj[ni]);
                    if (lt & same) { pos += fmaxf(d2, 0.f); cnt += 1.f; }
                    mn = fminf(mn, (lt & !same) ? d2 : 1e30f);
                }
        }
    } else {
        #pragma unroll
        for (int mi = 0; mi < 8; ++mi) {
            float4 sx4 = *(const float4*)&SXa[i0 + il + mi*16];
            float sxr[4] = {sx4.x, sx4.y, sx4.z, sx4.w};
            #pragma unroll
            for (int ni = 0; ni < 4; ++ni)
                #pragma unroll
                for (int r = 0; r < 4; ++r) {
                    float d2 = __builtin_fmaf(-2.f, acc[mi][ni][r],
                                              sxr[r] + tbv[ni]);
                    mn = fminf(mn, d2);
                }
        }
    }

    // rare exact path: only if some margin-active pair exists (never on this data)
    if (__any(mn < 1.f)) {
        int labj[4] = {0,0,0,0};
        if (jj)
            #pragma unroll
            for (int ni = 0; ni < 4; ++ni)
                labj[ni] = labels[tj * BM + jl + ni*16];
        const bool difftile = (ti != tj);
        #pragma unroll
        for (int mi = 0; mi < 8; ++mi) {
            float4 sx4 = *(const float4*)&SXa[i0 + il + mi*16];
            float sxr[4] = {sx4.x, sx4.y, sx4.z, sx4.w};
            int lar[4] = {0,0,0,0};
            if (jj) {
                int4 la4 = *(const int4*)&labels[i0 + il + mi*16];
                lar[0]=la4.x; lar[1]=la4.y; lar[2]=la4.z; lar[3]=la4.w;
            }
            #pragma unroll
            for (int ni = 0; ni < 4; ++ni)
                #pragma unroll
                for (int r = 0; r < 4; ++r) {
                    float d2 = __builtin_fmaf(-2.f, acc[mi][ni][r],
                                              sxr[r] + tbv[ni]);
                    d2 = fmaxf(d2, 0.f);
                    float dist = sqrtf(fmaxf(d2, 1e-12f));
                    float m = fmaxf(1.f - dist, 0.f);
                    float s2 = m * m;
                    if (jj) {
                        bool lt   = difftile | ((il + mi*16 + r) < (jl + ni*16));
                        bool same = (lar[r] == labj[ni]);
                        if (lt & !same) neg += s2;
                    } else {
                        cross += s2;
                    }
                }
        }
    }

    #pragma unroll
    for (int o = 32; o; o >>= 1) {
        pos   += __shfl_down(pos, o);
        neg   += __shfl_down(neg, o);
        cross += __shfl_down(cross, o);
        cnt   += __shfl_down(cnt, o);
    }
    if (lane == 0) { red[wave][0] = pos; red[wave][1] = neg;
                     red[wave][2] = cross; red[wave][3] = cnt; }
    __syncthreads();
    if (t == 0) {
        float4 v = {0.f, 0.f, 0.f, 0.f};
        #pragma unroll
        for (int w = 0; w < 8; ++w) {
            v.x += red[w][0]; v.y += red[w][1];
            v.z += red[w][2]; v.w += red[w][3];
        }
        partials[bid] = v;
    }
#undef STAGE_A
#undef STAGE_B
#undef PHASE
#undef FENCE
#undef BAR
#undef VMW4
#undef VMW0
}

// ---------------- final reduce ----------------
__global__ __launch_bounds__(256)
void finalize_kernel(const float4* __restrict__ partials, float* __restrict__ out) {
    int t = threadIdx.x;
    double p = 0, n = 0, c = 0, k = 0;
    for (int s = t; s < NBLK; s += 256) {
        float4 v = partials[s];
        p += v.x; n += v.y; c += v.z; k += v.w;
    }
    __shared__ double sh[256][4];
    sh[t][0] = p; sh[t][1] = n; sh[t][2] = c; sh[t][3] = k;
    __syncthreads();
    for (int o = 128; o; o >>= 1) {
        if (t < o) {
            sh[t][0] += sh[t+o][0]; sh[t][1] += sh[t+o][1];
            sh[t][2] += sh[t+o][2]; sh[t][3] += sh[t+o][3];
        }
        __syncthreads();
    }
    if (t == 0) {
        double npos = sh[0][3] < 1.0 ? 1.0 : sh[0][3];
        double total = (double)NROWS * (NROWS - 1) * 0.5;
        double nneg = total - sh[0][3]; if (nneg < 1.0) nneg = 1.0;
        double loss = sh[0][0] / npos + sh[0][1] / nneg
                    + sh[0][2] / ((double)NROWS * (double)NROWS);
        out[0] = (float)loss;
    }
}

extern "C" void kernel_launch(void* const* d_in, const int* in_sizes, int n_in,
                              void* d_out, int out_size, void* d_ws, size_t ws_size,
                              hipStream_t stream) {
    const float* X      = (const float*)d_in[0];
    const float* Y      = (const float*)d_in[1];
    const int*   labels = (const int*)d_in[2];
    float* out = (float*)d_out;
    char*  ws  = (char*)d_ws;

    // ws: partials (128KB) | SXa (32KB) | TB (64KB) | Zf8 (16384*768 = 12.6MB)
    float4* partials = (float4*)ws;
    float*  SXa      = (float*)(ws + 128*1024);
    float*  TB       = (float*)(ws + 128*1024 + 32*1024);
    uchar*  Zf8      = (uchar*)(ws + 256*1024);

    prep<<<2 * NROWS, 256, 0, stream>>>(X, Y, SXa, TB, Zf8);
    gemm_loss<<<NBLK, 512, 0, stream>>>(Zf8, labels, SXa, TB, partials);
    finalize_kernel<<<1, 256, 0, stream>>>(partials, out);
}

// Round 10
// 907.388 us; speedup vs baseline: 1.1941x; 1.1380x over previous
//
#include <hip/hip_runtime.h>
#include <hip/hip_bf16.h>
#include <stdint.h>
#include <math.h>

#define NROWS  8192
#define DIM    768                        // elements per row (1 B each in fp8)
#define BK     128                        // K per tile (fp8 bytes) = MFMA K
#define NKT    (DIM / BK)                 // 6 K-tiles -> 3 iterations x 2 tiles
#define BM     256
#define NTILE2 32                         // 8192/256
#define EPSV   1e-6f
#define NJN    (NTILE2 * NTILE2)           // 1024 X-vs-Y tiles
#define NJJ    (NTILE2 * (NTILE2 + 1) / 2) // 528 upper-tri X-vs-X tiles
#define NBLK   (NJN + NJJ)                 // 1552 = 8 * 194 (XCD-divisible)

typedef __attribute__((ext_vector_type(4))) int   int4v;
typedef __attribute__((ext_vector_type(8))) int   int8v;
typedef __attribute__((ext_vector_type(4))) float f32x4;
typedef unsigned char uchar;

// async global->LDS, 16B per lane; LDS dest is wave-uniform base (+lane*16 by HW)
__device__ __forceinline__ void gload16(const void* g, void* l) {
    __builtin_amdgcn_global_load_lds(
        (const __attribute__((address_space(1))) void*)g,
        (__attribute__((address_space(3))) void*)l,
        16, 0, 0);
}

// ------- prep: fp8-e4m3 convert into Z=[X;Y], folded row stats (exact fp32) -------
__global__ __launch_bounds__(256)
void prep(const float* __restrict__ X, const float* __restrict__ Y,
          float* __restrict__ SXa, float* __restrict__ TB,
          uchar* __restrict__ Zf8) {
    int row = blockIdx.x;                  // 0..16383
    bool isX = row < NROWS;
    const float* p = (isX ? X : Y) + (size_t)(isX ? row : row - NROWS) * DIM;
    uint32_t* q = (uint32_t*)(Zf8 + (size_t)row * DIM);
    int t = threadIdx.x;
    float s = 0.f, qs = 0.f;
    if (t < 192) {                         // 192 * 4 = 768 elems
        float4 v = *(const float4*)(p + 4 * t);
        uint32_t u = __builtin_amdgcn_cvt_pk_fp8_f32(v.x, v.y, 0u, false);
        u = __builtin_amdgcn_cvt_pk_fp8_f32(v.z, v.w, u, true);
        q[t] = u;
        s  = v.x + v.y + v.z + v.w;
        qs = v.x*v.x + v.y*v.y + v.z*v.z + v.w*v.w;
    }
    #pragma unroll
    for (int o = 32; o; o >>= 1) { s += __shfl_down(s, o); qs += __shfl_down(qs, o); }
    __shared__ float sh[8];
    int wave = t >> 6, lane = t & 63;
    if (lane == 0) { sh[wave] = s; sh[4 + wave] = qs; }
    __syncthreads();
    if (t == 0) {
        float ss = sh[0]+sh[1]+sh[2]+sh[3];
        float qq = sh[4]+sh[5]+sh[6]+sh[7];
        if (isX) SXa[row] = qq + 2.f*EPSV*ss;
        TB[row] = qq - 2.f*EPSV*ss + (float)DIM*EPSV*EPSV;
    }
}

// ------- fused MX-fp8 GEMM, 256x256, 8 waves, 8-phase v2 (race-free, low-VGPR) ----
// LDS swizzle (both-sides involution, verified r5-r9): LDS[row][c] holds global
// element col c^((row&7)<<4); linear gload_lds dest + pre-swizzled global source;
// ds_read applies the same XOR.
// Schedule per iteration I (tiles 2I in buf0, 2I+1 in buf1), quadrant phases:
//   ph1(b0,q00)+stageA(2I+1->b1)  ph2(b0,q01)+stageB(2I+1->b1)
//   ph3(b0,q10)                   ph4(b0,q11)+VMW0  <- gates buf1 ready
//   ph5(b1,q00)+stageA(2I+2->b0)  ph6(b1,q01)+stageB(2I+2->b0)
//   ph7(b1,q10)                   ph8(b1,q11)+VMW0  <- gates buf0 ready
// Stages ALWAYS target the buffer NOT being read this half -> WAR gated by the
// half-iteration barriers. Each wave's VMW0 precedes its BAR, so barrier-release
// implies all waves' loads landed (cross-wave RAW safe). Register budget: only
// bfr[2] (16 VGPRs) lives across a barrier; afr loaded inside the MFMA cluster
// (r8/r9 spilled: acc=128 AGPR leaves 128 arch VGPRs; 48-reg fragment preload
// + phase state exceeded it -> 2.7GB scratch traffic).
__global__ __launch_bounds__(512, 1)
void gemm_loss(const uchar* __restrict__ Z, const int* __restrict__ labels,
               const float* __restrict__ SXa, const float* __restrict__ TB,
               float4* __restrict__ partials) {
    // bijective XCD swizzle: 1552 = 8 * 194
    const int bid = (blockIdx.x & 7) * (NBLK / 8) + (blockIdx.x >> 3);
    const int t = threadIdx.x;

    int ti, tj, jrow0;                      // jrow0 = B-side row base in Z
    bool jj;
    if (bid < NJN) {
        jj = false; ti = bid >> 5; tj = bid & 31; jrow0 = NROWS + tj * BM;
    } else {
        jj = true;
        int u = bid - NJN;                  // 0..527, upper-tri (ti<=tj), 32 rows
        int t0 = (int)((65.0 - sqrt(65.0*65.0 - 8.0*(double)u)) * 0.5);
        if (t0 < 0) t0 = 0; if (t0 > 31) t0 = 31;
        while (t0 < 31 && (t0 + 1) * (65 - (t0 + 1)) / 2 <= u) ++t0;
        while (t0 > 0  && t0 * (65 - t0) / 2 > u) --t0;
        ti = t0; tj = ti + (u - ti * (65 - ti) / 2); jrow0 = tj * BM;
    }
    const int i0 = ti * BM;

    __shared__ __align__(16) uchar Asm[2][BM * BK];   // 32 KB per buf
    __shared__ __align__(16) uchar Bsm[2][BM * BK];
    __shared__ float red[8][4];

    const int wave = t >> 6, lane = t & 63;
    const int wr = wave >> 2;               // 0..1 (M half: 128 rows)
    const int wc = wave & 3;                // 0..3 (N quarter: 64 cols)

    // staging source: row&7 == lane>>3 always, so inverse-swizzled col is:
    const int cS = ((lane & 7) * 16) ^ ((lane >> 3) << 4);
    const int lB = (wave >> 2) * 64 + (wave & 3) * 8;     // B LDS row base/wave
    const uchar* pAs = Z + (size_t)(i0 + wave * 8 + (lane >> 3)) * DIM + cS;
    const uchar* pBs = Z + (size_t)(jrow0 + lB + (lane >> 3)) * DIM + cS;

    const int lrow = lane & 15;
    const int kg   = (lane >> 4) * 32;      // 32-byte K-group per lane quarter

    f32x4 acc[8][4] = {};

#define STAGE_A(d, h, kb)                                                      \
    do {                                                                       \
        gload16(pAs + (size_t)((h)*64)       * DIM + (kb),                     \
                &Asm[d][((h)*64 + wave*8) * 128]);                             \
        gload16(pAs + (size_t)(128 + (h)*64) * DIM + (kb),                     \
                &Asm[d][(128 + (h)*64 + wave*8) * 128]);                       \
    } while (0)

#define STAGE_B(d, h, kb)                                                      \
    do {                                                                       \
        gload16(pBs + (size_t)((h)*32)       * DIM + (kb),                     \
                &Bsm[d][(lB + (h)*32) * 128]);                                 \
        gload16(pBs + (size_t)(128 + (h)*32) * DIM + (kb),                     \
                &Bsm[d][(lB + 128 + (h)*32) * 128]);                           \
    } while (0)

#define FENCE() asm volatile("" ::: "memory")
#define BAR()   do { FENCE(); __builtin_amdgcn_s_barrier(); FENCE(); } while (0)
#define VMW0()  asm volatile("s_waitcnt vmcnt(0)" ::: "memory")

#define PHASE(d, mh, nh, STAGE_CODE, WAIT_CODE)                                \
    do {                                                                       \
        int8v bfr[2];                                                          \
        _Pragma("unroll")                                                      \
        for (int ni = 0; ni < 2; ++ni) {                                       \
            int rr = wc*64 + ((nh)*2 + ni)*16 + lrow;                          \
            int sw = (rr & 7) << 4;                                            \
            int4v lo = *(const int4v*)&Bsm[d][rr*128 + (kg ^ sw)];             \
            int4v hi = *(const int4v*)&Bsm[d][rr*128 + ((kg + 16) ^ sw)];      \
            bfr[ni] = __builtin_shufflevector(lo, hi, 0,1,2,3,4,5,6,7);        \
        }                                                                      \
        STAGE_CODE;                                                            \
        WAIT_CODE;                                                             \
        BAR();                                                                 \
        __builtin_amdgcn_s_setprio(1);                                         \
        _Pragma("unroll")                                                      \
        for (int mi = 0; mi < 4; ++mi) {                                       \
            int rr = wr*128 + ((mh)*4 + mi)*16 + lrow;                         \
            int sw = (rr & 7) << 4;                                            \
            int4v lo = *(const int4v*)&Asm[d][rr*128 + (kg ^ sw)];             \
            int4v hi = *(const int4v*)&Asm[d][rr*128 + ((kg + 16) ^ sw)];      \
            int8v afr = __builtin_shufflevector(lo, hi, 0,1,2,3,4,5,6,7);      \
            acc[(mh)*4 + mi][(nh)*2 + 0] =                                     \
                __builtin_amdgcn_mfma_scale_f32_16x16x128_f8f6f4(              \
                    afr, bfr[0], acc[(mh)*4 + mi][(nh)*2 + 0],                 \
                    0, 0, 0, 0x7F7F7F7Fu, 0, 0x7F7F7F7Fu);                     \
            acc[(mh)*4 + mi][(nh)*2 + 1] =                                     \
                __builtin_amdgcn_mfma_scale_f32_16x16x128_f8f6f4(              \
                    afr, bfr[1], acc[(mh)*4 + mi][(nh)*2 + 1],                 \
                    0, 0, 0, 0x7F7F7F7Fu, 0, 0x7F7F7F7Fu);                     \
        }                                                                      \
        __builtin_amdgcn_s_setprio(0);                                         \
        BAR();                                                                 \
    } while (0)

    // prologue: stage tile0 -> buf0 (8 loads), drain, barrier
    STAGE_A(0, 0, 0); STAGE_A(0, 1, 0); STAGE_B(0, 0, 0); STAGE_B(0, 1, 0);
    VMW0();
    BAR();

    #pragma unroll 1
    for (int it = 0; it < 3; ++it) {
        const int kOdd  = (2*it + 1) * BK;   // tile 2I+1 -> buf1
        const int kEven = (2*it + 2) * BK;   // tile 2I+2 -> buf0
        const bool more = (it < 2);
        // half 1: compute buf0 (tile 2I); stage buf1
        PHASE(0, 0, 0, { STAGE_A(1, 0, kOdd); STAGE_A(1, 1, kOdd); }, {});
        PHASE(0, 0, 1, { STAGE_B(1, 0, kOdd); STAGE_B(1, 1, kOdd); }, {});
        PHASE(0, 1, 0, {}, {});
        PHASE(0, 1, 1, {}, { VMW0(); });                 // gate: buf1 ready
        // half 2: compute buf1 (tile 2I+1); stage buf0
        PHASE(1, 0, 0, { if (more) { STAGE_A(0, 0, kEven); STAGE_A(0, 1, kEven); } }, {});
        PHASE(1, 0, 1, { if (more) { STAGE_B(0, 0, kEven); STAGE_B(0, 1, kEven); } }, {});
        PHASE(1, 1, 0, {}, {});
        PHASE(1, 1, 1, {}, { if (more) VMW0(); });       // gate: buf0 ready
    }

    // -------- epilogue (C/D: col=lane&15, row=(lane>>4)*4+reg) --------
    const int il = wr*128 + ((lane >> 4) << 2);  // + mi*16 + r
    const int jl = wc*64 + (lane & 15);          // + ni*16

    float tbv[4];
    #pragma unroll
    for (int ni = 0; ni < 4; ++ni)
        tbv[ni] = TB[jrow0 + jl + ni*16];

    float pos = 0.f, neg = 0.f, cross = 0.f, cnt = 0.f;
    float mn = 1e30f;                        // min over valid neg/cross cands

    if (jj) {
        int labj[4];
        #pragma unroll
        for (int ni = 0; ni < 4; ++ni)
            labj[ni] = labels[tj * BM + jl + ni*16];
        const bool difftile = (ti != tj);
        #pragma unroll
        for (int mi = 0; mi < 8; ++mi) {
            float4 sx4 = *(const float4*)&SXa[i0 + il + mi*16];
            int4   la4 = *(const int4*)&labels[i0 + il + mi*16];
            float sxr[4] = {sx4.x, sx4.y, sx4.z, sx4.w};
            int   lar[4] = {la4.x, la4.y, la4.z, la4.w};
            #pragma unroll
            for (int ni = 0; ni < 4; ++ni)
                #pragma unroll
                for (int r = 0; r < 4; ++r) {
                    float d2 = __builtin_fmaf(-2.f, acc[mi][ni][r],
                                              sxr[r] + tbv[ni]);
                    bool lt   = difftile | ((il + mi*16 + r) < (jl + ni*16));
                    bool same = (lar[r] == labj[ni]);
                    if (lt & same) { pos += fmaxf(d2, 0.f); cnt += 1.f; }
                    mn = fminf(mn, (lt & !same) ? d2 : 1e30f);
                }
        }
    } else {
        #pragma unroll
        for (int mi = 0; mi < 8; ++mi) {
            float4 sx4 = *(const float4*)&SXa[i0 + il + mi*16];
            float sxr[4] = {sx4.x, sx4.y, sx4.z, sx4.w};
            #pragma unroll
            for (int ni = 0; ni < 4; ++ni)
                #pragma unroll
                for (int r = 0; r < 4; ++r) {
                    float d2 = __builtin_fmaf(-2.f, acc[mi][ni][r],
                                              sxr[r] + tbv[ni]);
                    mn = fminf(mn, d2);
                }
        }
    }

    // rare exact path: only if some margin-active pair exists (never on this data)
    if (__any(mn < 1.f)) {
        int labj[4] = {0,0,0,0};
        if (jj)
            #pragma unroll
            for (int ni = 0; ni < 4; ++ni)
                labj[ni] = labels[tj * BM + jl + ni*16];
        const bool difftile = (ti != tj);
        #pragma unroll
        for (int mi = 0; mi < 8; ++mi) {
            float4 sx4 = *(const float4*)&SXa[i0 + il + mi*16];
            float sxr[4] = {sx4.x, sx4.y, sx4.z, sx4.w};
            int lar[4] = {0,0,0,0};
            if (jj) {
                int4 la4 = *(const int4*)&labels[i0 + il + mi*16];
                lar[0]=la4.x; lar[1]=la4.y; lar[2]=la4.z; lar[3]=la4.w;
            }
            #pragma unroll
            for (int ni = 0; ni < 4; ++ni)
                #pragma unroll
                for (int r = 0; r < 4; ++r) {
                    float d2 = __builtin_fmaf(-2.f, acc[mi][ni][r],
                                              sxr[r] + tbv[ni]);
                    d2 = fmaxf(d2, 0.f);
                    float dist = sqrtf(fmaxf(d2, 1e-12f));
                    float m = fmaxf(1.f - dist, 0.f);
                    float s2 = m * m;
                    if (jj) {
                        bool lt   = difftile | ((il + mi*16 + r) < (jl + ni*16));
                        bool same = (lar[r] == labj[ni]);
                        if (lt & !same) neg += s2;
                    } else {
                        cross += s2;
                    }
                }
        }
    }

    #pragma unroll
    for (int o = 32; o; o >>= 1) {
        pos   += __shfl_down(pos, o);
        neg   += __shfl_down(neg, o);
        cross += __shfl_down(cross, o);
        cnt   += __shfl_down(cnt, o);
    }
    if (lane == 0) { red[wave][0] = pos; red[wave][1] = neg;
                     red[wave][2] = cross; red[wave][3] = cnt; }
    __syncthreads();
    if (t == 0) {
        float4 v = {0.f, 0.f, 0.f, 0.f};
        #pragma unroll
        for (int w = 0; w < 8; ++w) {
            v.x += red[w][0]; v.y += red[w][1];
            v.z += red[w][2]; v.w += red[w][3];
        }
        partials[bid] = v;
    }
#undef STAGE_A
#undef STAGE_B
#undef PHASE
#undef FENCE
#undef BAR
#undef VMW0
}

// ---------------- final reduce ----------------
__global__ __launch_bounds__(256)
void finalize_kernel(const float4* __restrict__ partials, float* __restrict__ out) {
    int t = threadIdx.x;
    double p = 0, n = 0, c = 0, k = 0;
    for (int s = t; s < NBLK; s += 256) {
        float4 v = partials[s];
        p += v.x; n += v.y; c += v.z; k += v.w;
    }
    __shared__ double sh[256][4];
    sh[t][0] = p; sh[t][1] = n; sh[t][2] = c; sh[t][3] = k;
    __syncthreads();
    for (int o = 128; o; o >>= 1) {
        if (t < o) {
            sh[t][0] += sh[t+o][0]; sh[t][1] += sh[t+o][1];
            sh[t][2] += sh[t+o][2]; sh[t][3] += sh[t+o][3];
        }
        __syncthreads();
    }
    if (t == 0) {
        double npos = sh[0][3] < 1.0 ? 1.0 : sh[0][3];
        double total = (double)NROWS * (NROWS - 1) * 0.5;
        double nneg = total - sh[0][3]; if (nneg < 1.0) nneg = 1.0;
        double loss = sh[0][0] / npos + sh[0][1] / nneg
                    + sh[0][2] / ((double)NROWS * (double)NROWS);
        out[0] = (float)loss;
    }
}

extern "C" void kernel_launch(void* const* d_in, const int* in_sizes, int n_in,
                              void* d_out, int out_size, void* d_ws, size_t ws_size,
                              hipStream_t stream) {
    const float* X      = (const float*)d_in[0];
    const float* Y      = (const float*)d_in[1];
    const int*   labels = (const int*)d_in[2];
    float* out = (float*)d_out;
    char*  ws  = (char*)d_ws;

    // ws: partials (128KB) | SXa (32KB) | TB (64KB) | Zf8 (16384*768 = 12.6MB)
    float4* partials = (float4*)ws;
    float*  SXa      = (float*)(ws + 128*1024);
    float*  TB       = (float*)(ws + 128*1024 + 32*1024);
    uchar*  Zf8      = (uchar*)(ws + 256*1024);

    prep<<<2 * NROWS, 256, 0, stream>>>(X, Y, SXa, TB, Zf8);
    gemm_loss<<<NBLK, 512, 0, stream>>>(Zf8, labels, SXa, TB, partials);
    finalize_kernel<<<1, 256, 0, stream>>>(partials, out);
}

// Round 11
// 155.103 us; speedup vs baseline: 6.9860x; 5.8502x over previous
//
#include <hip/hip_runtime.h>
#include <hip/hip_bf16.h>
#include <stdint.h>
#include <math.h>

#define NROWS  8192
#define DIM    768                        // elements per row (1 B each in fp8)
#define BK     128                        // K per tile (fp8 bytes) = MFMA K
#define NKT    (DIM / BK)                 // 6 K-tiles
#define BM     256
#define BN     128
#define EPSV   1e-6f
#define NTI    32                         // 8192/BM
#define NTJ    64                         // 8192/BN
#define NJN    (NTI * NTJ)                // 2048 X-vs-Y tiles
#define NJJ    1056                       // JJ tiles: sum_{ti}(64-2ti)
#define NBLK   (NJN + NJJ)                // 3104 = 8 * 388 (XCD-divisible)

typedef __attribute__((ext_vector_type(4))) int   int4v;
typedef __attribute__((ext_vector_type(8))) int   int8v;
typedef __attribute__((ext_vector_type(4))) float f32x4;
typedef unsigned char uchar;

// async global->LDS, 16B per lane; LDS dest is wave-uniform base (+lane*16 by HW)
__device__ __forceinline__ void gload16(const void* g, void* l) {
    __builtin_amdgcn_global_load_lds(
        (const __attribute__((address_space(1))) void*)g,
        (__attribute__((address_space(3))) void*)l,
        16, 0, 0);
}

// ------- prep: fp8-e4m3 convert into Z=[X;Y], folded row stats (exact fp32) -------
__global__ __launch_bounds__(256)
void prep(const float* __restrict__ X, const float* __restrict__ Y,
          float* __restrict__ SXa, float* __restrict__ TB,
          uchar* __restrict__ Zf8) {
    int row = blockIdx.x;                  // 0..16383
    bool isX = row < NROWS;
    const float* p = (isX ? X : Y) + (size_t)(isX ? row : row - NROWS) * DIM;
    uint32_t* q = (uint32_t*)(Zf8 + (size_t)row * DIM);
    int t = threadIdx.x;
    float s = 0.f, qs = 0.f;
    if (t < 192) {                         // 192 * 4 = 768 elems
        float4 v = *(const float4*)(p + 4 * t);
        uint32_t u = __builtin_amdgcn_cvt_pk_fp8_f32(v.x, v.y, 0u, false);
        u = __builtin_amdgcn_cvt_pk_fp8_f32(v.z, v.w, u, true);
        q[t] = u;
        s  = v.x + v.y + v.z + v.w;
        qs = v.x*v.x + v.y*v.y + v.z*v.z + v.w*v.w;
    }
    #pragma unroll
    for (int o = 32; o; o >>= 1) { s += __shfl_down(s, o); qs += __shfl_down(qs, o); }
    __shared__ float sh[8];
    int wave = t >> 6, lane = t & 63;
    if (lane == 0) { sh[wave] = s; sh[4 + wave] = qs; }
    __syncthreads();
    if (t == 0) {
        float ss = sh[0]+sh[1]+sh[2]+sh[3];
        float qq = sh[4]+sh[5]+sh[6]+sh[7];
        if (isX) SXa[row] = qq + 2.f*EPSV*ss;
        TB[row] = qq - 2.f*EPSV*ss + (float)DIM*EPSV*EPSV;
    }
}

// ------- fused MX-fp8 GEMM, 256x128 tile, 8 waves (4Mx2N), 3-deep pipeline -------
// LDS swizzle (both-sides involution, verified r5-r10): LDS[row][c] holds global
// element col c^((row&7)<<4); linear gload_lds dest + pre-swizzled global source;
// ds_read applies the same XOR.
// Register budget: acc = 4x4 f32x4 = 64 regs -> ~190 arch VGPRs free (r8-r10
// lesson: unified file = 256/wave at 8 waves/CU; acc=128 capped arch at 128 and
// ANY extra live state spilled -> GBs of scratch).
// Pipeline: 3 LDS buffers (48KB each; 144KB total), stage tile t+2 at iter t,
// trailing VMW6 retires tile t+1's 6 loads (cover ~= 2 compute clusters ~3K cy
// >> HBM latency). WAR: stage(buf (t+2)%3) follows iter t-1's trailing BAR,
// which seals tile t-1's reads of that same buffer. 7 barriers/block total.
__global__ __launch_bounds__(512, 1)
void gemm_loss(const uchar* __restrict__ Z, const int* __restrict__ labels,
               const float* __restrict__ SXa, const float* __restrict__ TB,
               float4* __restrict__ partials) {
    // bijective XCD swizzle: 3104 = 8 * 388
    const int bid = (blockIdx.x & 7) * (NBLK / 8) + (blockIdx.x >> 3);
    const int t = threadIdx.x;

    int ti, tj, jrow0;                      // jrow0 = B-side row base in Z
    bool jj;
    if (bid < NJN) {
        jj = false; ti = bid >> 6; tj = bid & 63; jrow0 = NROWS + tj * BN;
    } else {
        jj = true;
        int u = bid - NJN;                  // 0..1055; row ti has 64-2ti entries
        // offset(ti) = ti*(65-ti), strictly increasing on [0,32)
        int t0 = (int)((65.0 - sqrt(65.0*65.0 - 4.0*(double)u)) * 0.5);
        if (t0 < 0) t0 = 0; if (t0 > 31) t0 = 31;
        while (t0 < 31 && (t0 + 1) * (65 - (t0 + 1)) <= u) ++t0;
        while (t0 > 0  && t0 * (65 - t0) > u) --t0;
        ti = t0; tj = 2*ti + (u - ti * (65 - ti)); jrow0 = tj * BN;
    }
    const int i0 = ti * BM;
    const int tjc = tj * BN;                // B-side column base (labels/lt)

    __shared__ __align__(16) uchar Asm[3][BM * BK];   // 32 KB per buf
    __shared__ __align__(16) uchar Bsm[3][BN * BK];   // 16 KB per buf
    __shared__ float red[8][4];

    const int wave = t >> 6, lane = t & 63;
    const int wrow = wave >> 1;             // 0..3 (M quarter: 64 rows)
    const int wcol = wave & 1;              // 0..1 (N half: 64 cols)

    // staging source: row&7 == lane>>3 always, so inverse-swizzled col is:
    const int cS = ((lane & 7) * 16) ^ ((lane >> 3) << 4);
    const uchar* pAs = Z + (size_t)(i0 + 8*wave + (lane >> 3))    * DIM + cS;
    const uchar* pBs = Z + (size_t)(jrow0 + 8*wave + (lane >> 3)) * DIM + cS;

    const int lrow = lane & 15;
    const int kg   = (lane >> 4) * 32;      // 32-byte K-group per lane quarter

    f32x4 acc[4][4] = {};

#define STAGE(b, kb)                                                           \
    do {                                                                       \
        _Pragma("unroll")                                                      \
        for (int qq = 0; qq < 4; ++qq)                                         \
            gload16(pAs + (size_t)qq*64*DIM + (kb),                            \
                    &Asm[b][(wave + 8*qq)*1024]);                              \
        gload16(pBs + (kb), &Bsm[b][wave*1024]);                               \
        gload16(pBs + (size_t)64*DIM + (kb), &Bsm[b][(wave + 8)*1024]);        \
    } while (0)

#define COMPUTE(b)                                                             \
    do {                                                                       \
        int8v bfr[4];                                                          \
        _Pragma("unroll")                                                      \
        for (int ni = 0; ni < 4; ++ni) {                                       \
            int rr = wcol*64 + ni*16 + lrow;                                   \
            int sw = (rr & 7) << 4;                                            \
            int4v lo = *(const int4v*)&Bsm[b][rr*128 + (kg ^ sw)];             \
            int4v hi = *(const int4v*)&Bsm[b][rr*128 + ((kg + 16) ^ sw)];      \
            bfr[ni] = __builtin_shufflevector(lo, hi, 0,1,2,3,4,5,6,7);        \
        }                                                                      \
        __builtin_amdgcn_s_setprio(1);                                         \
        _Pragma("unroll")                                                      \
        for (int mi = 0; mi < 4; ++mi) {                                       \
            int rr = wrow*64 + mi*16 + lrow;                                   \
            int sw = (rr & 7) << 4;                                            \
            int4v lo = *(const int4v*)&Asm[b][rr*128 + (kg ^ sw)];             \
            int4v hi = *(const int4v*)&Asm[b][rr*128 + ((kg + 16) ^ sw)];      \
            int8v afr = __builtin_shufflevector(lo, hi, 0,1,2,3,4,5,6,7);      \
            _Pragma("unroll")                                                  \
            for (int ni = 0; ni < 4; ++ni)                                     \
                acc[mi][ni] = __builtin_amdgcn_mfma_scale_f32_16x16x128_f8f6f4( \
                    afr, bfr[ni], acc[mi][ni], 0, 0,                           \
                    0, 0x7F7F7F7Fu, 0, 0x7F7F7F7Fu);                           \
        }                                                                      \
        __builtin_amdgcn_s_setprio(0);                                         \
    } while (0)

#define FENCE() asm volatile("" ::: "memory")
#define BAR()   do { FENCE(); __builtin_amdgcn_s_barrier(); FENCE(); } while (0)
#define VMW6()  asm volatile("s_waitcnt vmcnt(6)" ::: "memory")
#define VMW0()  asm volatile("s_waitcnt vmcnt(0)" ::: "memory")

    // prologue: stage tiles 0,1; retire tile 0 (VMW6 leaves tile 1's 6 in flight)
    STAGE(0, 0);
    STAGE(1, BK);
    VMW6();
    BAR();

    #pragma unroll
    for (int kt = 0; kt < NKT; ++kt) {
        if (kt < NKT - 2) STAGE((kt + 2) % 3, (kt + 2) * BK);
        COMPUTE(kt % 3);
        if (kt < NKT - 2)      { VMW6(); BAR(); }   // retire tile kt+1
        else if (kt == NKT - 2){ VMW0(); BAR(); }   // tail: tile kt+1 fully in
    }

    // -------- epilogue (C/D: col=lane&15, row=(lane>>4)*4+reg) --------
    const int il = wrow*64 + ((lane >> 4) << 2);  // + mi*16 + r
    const int jl = wcol*64 + (lane & 15);         // + ni*16

    float tbv[4];
    #pragma unroll
    for (int ni = 0; ni < 4; ++ni)
        tbv[ni] = TB[jrow0 + jl + ni*16];

    float pos = 0.f, neg = 0.f, cross = 0.f, cnt = 0.f;
    float mn = 1e30f;                        // min over valid neg/cross cands

    if (jj) {
        int labj[4];
        #pragma unroll
        for (int ni = 0; ni < 4; ++ni)
            labj[ni] = labels[tjc + jl + ni*16];
        const bool fullup = (tj >= 2*ti + 2);    // tile strictly above diagonal
        #pragma unroll
        for (int mi = 0; mi < 4; ++mi) {
            float4 sx4 = *(const float4*)&SXa[i0 + il + mi*16];
            int4   la4 = *(const int4*)&labels[i0 + il + mi*16];
            float sxr[4] = {sx4.x, sx4.y, sx4.z, sx4.w};
            int   lar[4] = {la4.x, la4.y, la4.z, la4.w};
            #pragma unroll
            for (int ni = 0; ni < 4; ++ni)
                #pragma unroll
                for (int r = 0; r < 4; ++r) {
                    float d2 = __builtin_fmaf(-2.f, acc[mi][ni][r],
                                              sxr[r] + tbv[ni]);
                    bool lt   = fullup | ((i0 + il + mi*16 + r) < (tjc + jl + ni*16));
                    bool same = (lar[r] == labj[ni]);
                    if (lt & same) { pos += fmaxf(d2, 0.f); cnt += 1.f; }
                    mn = fminf(mn, (lt & !same) ? d2 : 1e30f);
                }
        }
    } else {
        #pragma unroll
        for (int mi = 0; mi < 4; ++mi) {
            float4 sx4 = *(const float4*)&SXa[i0 + il + mi*16];
            float sxr[4] = {sx4.x, sx4.y, sx4.z, sx4.w};
            #pragma unroll
            for (int ni = 0; ni < 4; ++ni)
                #pragma unroll
                for (int r = 0; r < 4; ++r) {
                    float d2 = __builtin_fmaf(-2.f, acc[mi][ni][r],
                                              sxr[r] + tbv[ni]);
                    mn = fminf(mn, d2);
                }
        }
    }

    // rare exact path: only if some margin-active pair exists (never on this data)
    if (__any(mn < 1.f)) {
        int labj[4] = {0,0,0,0};
        if (jj)
            #pragma unroll
            for (int ni = 0; ni < 4; ++ni)
                labj[ni] = labels[tjc + jl + ni*16];
        const bool fullup = jj && (tj >= 2*ti + 2);
        #pragma unroll
        for (int mi = 0; mi < 4; ++mi) {
            float4 sx4 = *(const float4*)&SXa[i0 + il + mi*16];
            float sxr[4] = {sx4.x, sx4.y, sx4.z, sx4.w};
            int lar[4] = {0,0,0,0};
            if (jj) {
                int4 la4 = *(const int4*)&labels[i0 + il + mi*16];
                lar[0]=la4.x; lar[1]=la4.y; lar[2]=la4.z; lar[3]=la4.w;
            }
            #pragma unroll
            for (int ni = 0; ni < 4; ++ni)
                #pragma unroll
                for (int r = 0; r < 4; ++r) {
                    float d2 = __builtin_fmaf(-2.f, acc[mi][ni][r],
                                              sxr[r] + tbv[ni]);
                    d2 = fmaxf(d2, 0.f);
                    float dist = sqrtf(fmaxf(d2, 1e-12f));
                    float m = fmaxf(1.f - dist, 0.f);
                    float s2 = m * m;
                    if (jj) {
                        bool lt   = fullup | ((i0 + il + mi*16 + r) < (tjc + jl + ni*16));
                        bool same = (lar[r] == labj[ni]);
                        if (lt & !same) neg += s2;
                    } else {
                        cross += s2;
                    }
                }
        }
    }

    #pragma unroll
    for (int o = 32; o; o >>= 1) {
        pos   += __shfl_down(pos, o);
        neg   += __shfl_down(neg, o);
        cross += __shfl_down(cross, o);
        cnt   += __shfl_down(cnt, o);
    }
    if (lane == 0) { red[wave][0] = pos; red[wave][1] = neg;
                     red[wave][2] = cross; red[wave][3] = cnt; }
    __syncthreads();
    if (t == 0) {
        float4 v = {0.f, 0.f, 0.f, 0.f};
        #pragma unroll
        for (int w = 0; w < 8; ++w) {
            v.x += red[w][0]; v.y += red[w][1];
            v.z += red[w][2]; v.w += red[w][3];
        }
        partials[bid] = v;
    }
#undef STAGE
#undef COMPUTE
#undef FENCE
#undef BAR
#undef VMW6
#undef VMW0
}

// ---------------- final reduce ----------------
__global__ __launch_bounds__(256)
void finalize_kernel(const float4* __restrict__ partials, float* __restrict__ out) {
    int t = threadIdx.x;
    double p = 0, n = 0, c = 0, k = 0;
    for (int s = t; s < NBLK; s += 256) {
        float4 v = partials[s];
        p += v.x; n += v.y; c += v.z; k += v.w;
    }
    __shared__ double sh[256][4];
    sh[t][0] = p; sh[t][1] = n; sh[t][2] = c; sh[t][3] = k;
    __syncthreads();
    for (int o = 128; o; o >>= 1) {
        if (t < o) {
            sh[t][0] += sh[t+o][0]; sh[t][1] += sh[t+o][1];
            sh[t][2] += sh[t+o][2]; sh[t][3] += sh[t+o][3];
        }
        __syncthreads();
    }
    if (t == 0) {
        double npos = sh[0][3] < 1.0 ? 1.0 : sh[0][3];
        double total = (double)NROWS * (NROWS - 1) * 0.5;
        double nneg = total - sh[0][3]; if (nneg < 1.0) nneg = 1.0;
        double loss = sh[0][0] / npos + sh[0][1] / nneg
                    + sh[0][2] / ((double)NROWS * (double)NROWS);
        out[0] = (float)loss;
    }
}

extern "C" void kernel_launch(void* const* d_in, const int* in_sizes, int n_in,
                              void* d_out, int out_size, void* d_ws, size_t ws_size,
                              hipStream_t stream) {
    const float* X      = (const float*)d_in[0];
    const float* Y      = (const float*)d_in[1];
    const int*   labels = (const int*)d_in[2];
    float* out = (float*)d_out;
    char*  ws  = (char*)d_ws;

    // ws: partials (128KB) | SXa (32KB) | TB (64KB) | Zf8 (16384*768 = 12.6MB)
    float4* partials = (float4*)ws;
    float*  SXa      = (float*)(ws + 128*1024);
    float*  TB       = (float*)(ws + 128*1024 + 32*1024);
    uchar*  Zf8      = (uchar*)(ws + 256*1024);

    prep<<<2 * NROWS, 256, 0, stream>>>(X, Y, SXa, TB, Zf8);
    gemm_loss<<<NBLK, 512, 0, stream>>>(Zf8, labels, SXa, TB, partials);
    finalize_kernel<<<1, 256, 0, stream>>>(partials, out);
}

// Round 12
// 99.115 us; speedup vs baseline: 10.9323x; 1.5649x over previous
//
#include <hip/hip_runtime.h>
#include <hip/hip_bf16.h>
#include <stdint.h>
#include <math.h>

#define NROWS  8192
#define DIM    768                        // elements per row
#define DIMB   384                        // bytes per row in fp4 (4 bits/elem)
#define BKB    64                         // K-tile bytes (128 elements)
#define NKT    6                          // 768 / 128
#define BM     256
#define BN     128
#define EPSV   1e-6f
#define NTI    32                         // 8192/BM
#define NTJ    64                         // 8192/BN
#define NJN    (NTI * NTJ)                // 2048 X-vs-Y tiles
#define NJJ    1056                       // JJ tiles: sum_{ti}(64-2ti)
#define NBLK   (NJN + NJJ)                // 3104 = 8 * 388 (XCD-divisible)

typedef __attribute__((ext_vector_type(4))) int   int4v;
typedef __attribute__((ext_vector_type(8))) int   int8v;
typedef __attribute__((ext_vector_type(4))) float f32x4;
typedef unsigned char uchar;

// async global->LDS, 16B per lane; LDS dest is wave-uniform base (+lane*16 by HW)
__device__ __forceinline__ void gload16(const void* g, void* l) {
    __builtin_amdgcn_global_load_lds(
        (const __attribute__((address_space(1))) void*)g,
        (__attribute__((address_space(3))) void*)l,
        16, 0, 0);
}

// fp32 -> fp4 e2m1 nibble, round-to-nearest. Levels {0,.5,1,1.5,2,3,4,6}.
__device__ __forceinline__ uint32_t f2fp4(float x) {
    float a = fabsf(x);
    uint32_t c;
    if (a < 1.25f)      c = a < 0.25f ? 0u : (a < 0.75f ? 1u : 2u);
    else if (a < 2.5f)  c = a < 1.75f ? 3u : 4u;
    else                c = a < 3.5f ? 5u : (a < 5.0f ? 6u : 7u);
    return c | (x < 0.f ? 8u : 0u);
}

// ------- prep: fp4-e2m1 convert into Z=[X;Y], folded row stats (exact fp32) -------
__global__ __launch_bounds__(256)
void prep(const float* __restrict__ X, const float* __restrict__ Y,
          float* __restrict__ SXa, float* __restrict__ TB,
          uchar* __restrict__ Zf4) {
    int row = blockIdx.x;                  // 0..16383
    bool isX = row < NROWS;
    const float* p = (isX ? X : Y) + (size_t)(isX ? row : row - NROWS) * DIM;
    uint32_t* q = (uint32_t*)(Zf4 + (size_t)row * DIMB);
    int t = threadIdx.x;
    float s = 0.f, qs = 0.f;
    if (t < 96) {                          // 96 * 8 = 768 elems
        float4 v0 = *(const float4*)(p + 8 * t);
        float4 v1 = *(const float4*)(p + 8 * t + 4);
        uint32_t u = f2fp4(v0.x)        | (f2fp4(v0.y) << 4)  |
                     (f2fp4(v0.z) << 8) | (f2fp4(v0.w) << 12) |
                     (f2fp4(v1.x) << 16)| (f2fp4(v1.y) << 20) |
                     (f2fp4(v1.z) << 24)| (f2fp4(v1.w) << 28);
        q[t] = u;
        s  = v0.x+v0.y+v0.z+v0.w + v1.x+v1.y+v1.z+v1.w;
        qs = v0.x*v0.x+v0.y*v0.y+v0.z*v0.z+v0.w*v0.w
           + v1.x*v1.x+v1.y*v1.y+v1.z*v1.z+v1.w*v1.w;
    }
    #pragma unroll
    for (int o = 32; o; o >>= 1) { s += __shfl_down(s, o); qs += __shfl_down(qs, o); }
    __shared__ float sh[8];
    int wave = t >> 6, lane = t & 63;
    if (lane == 0) { sh[wave] = s; sh[4 + wave] = qs; }
    __syncthreads();
    if (t == 0) {
        float ss = sh[0]+sh[1];            // waves 2,3 inactive (t>=128)
        float qq = sh[4]+sh[5];
        if (isX) SXa[row] = qq + 2.f*EPSV*ss;
        TB[row] = qq - 2.f*EPSV*ss + (float)DIM*EPSV*EPSV;
    }
}

// ------- fused MX-fp4 GEMM, 256x128 tile, 8 waves (4Mx2N), 3-deep pipeline -------
// LDS swizzle (involution, 64B rows): LDS byte (row, c) holds global byte
// c ^ ((row&3)<<4); linear gload_lds dest + pre-swizzled global source; ds_read
// applies the same XOR. 16 lanes/frag spread over 8 16B-slots -> 2-way (free).
// LDS: 3 bufs x (A 16KB + B 8KB) = 72KB -> 2 blocks/CU (the r5-r11 configs were
// stuck at 1 block/CU; cross-block overlap hides prologue/epilogue/barriers).
// launch_bounds(512,4): 4 waves/EU -> 2 blocks/CU, reg cap 128 (r11 used 88).
// Pipeline (r11-verified): stage tile t+2 at iter t, trailing VMW3 retires tile
// t+1's 3 loads/wave. fp4 MFMA: cbsz=4/blgp=4, operand = 4 regs (low half).
__global__ __launch_bounds__(512, 4)
void gemm_loss(const uchar* __restrict__ Z, const int* __restrict__ labels,
               const float* __restrict__ SXa, const float* __restrict__ TB,
               float4* __restrict__ partials) {
    // bijective XCD swizzle: 3104 = 8 * 388
    const int bid = (blockIdx.x & 7) * (NBLK / 8) + (blockIdx.x >> 3);
    const int t = threadIdx.x;

    int ti, tj, jrow0;                      // jrow0 = B-side row base in Z
    bool jj;
    if (bid < NJN) {
        jj = false; ti = bid >> 6; tj = bid & 63; jrow0 = NROWS + tj * BN;
    } else {
        jj = true;
        int u = bid - NJN;                  // 0..1055; row ti has 64-2ti entries
        int t0 = (int)((65.0 - sqrt(65.0*65.0 - 4.0*(double)u)) * 0.5);
        if (t0 < 0) t0 = 0; if (t0 > 31) t0 = 31;
        while (t0 < 31 && (t0 + 1) * (65 - (t0 + 1)) <= u) ++t0;
        while (t0 > 0  && t0 * (65 - t0) > u) --t0;
        ti = t0; tj = 2*ti + (u - ti * (65 - ti)); jrow0 = tj * BN;
    }
    const int i0 = ti * BM;
    const int tjc = tj * BN;                // B-side column base (labels/lt)

    __shared__ __align__(16) uchar Asm[3][BM * BKB];   // 16 KB per buf
    __shared__ __align__(16) uchar Bsm[3][BN * BKB];   // 8 KB per buf
    __shared__ float red[8][4];

    const int wave = t >> 6, lane = t & 63;
    const int wrow = wave >> 1;             // 0..3 (M quarter: 64 rows)
    const int wcol = wave & 1;              // 0..1 (N half: 64 cols)

    // staging: chunk = 16 rows x 64B = 1KB; lane l -> row +(l>>2), slot l&3;
    // inverse-swizzled global col bytes:
    const int cS = ((lane & 3) * 16) ^ (((lane >> 2) & 3) << 4);
    const uchar* pAs = Z + (size_t)(i0 + 16*wave + (lane >> 2))    * DIMB + cS;
    const uchar* pBs = Z + (size_t)(jrow0 + 16*wave + (lane >> 2)) * DIMB + cS;

    const int lrow = lane & 15;
    const int kc   = (lane >> 4) * 16;      // 16-byte K-slot per lane quarter

    f32x4 acc[4][4] = {};

#define STAGE(b, kb)                                                           \
    do {                                                                       \
        gload16(pAs + (kb), &Asm[b][wave * 1024]);                             \
        gload16(pAs + (size_t)128 * DIMB + (kb), &Asm[b][(wave + 8) * 1024]);  \
        gload16(pBs + (kb), &Bsm[b][wave * 1024]);                             \
    } while (0)

#define COMPUTE(b)                                                             \
    do {                                                                       \
        int8v bfr[4];                                                          \
        _Pragma("unroll")                                                      \
        for (int ni = 0; ni < 4; ++ni) {                                       \
            int rr = wcol*64 + ni*16 + lrow;                                   \
            int4v lo = *(const int4v*)&Bsm[b][rr*64 + (kc ^ ((rr & 3) << 4))]; \
            bfr[ni] = __builtin_shufflevector(lo, (int4v){0,0,0,0},            \
                                              0,1,2,3,4,5,6,7);                \
        }                                                                      \
        __builtin_amdgcn_s_setprio(1);                                         \
        _Pragma("unroll")                                                      \
        for (int mi = 0; mi < 4; ++mi) {                                       \
            int rr = wrow*64 + mi*16 + lrow;                                   \
            int4v lo = *(const int4v*)&Asm[b][rr*64 + (kc ^ ((rr & 3) << 4))]; \
            int8v afr = __builtin_shufflevector(lo, (int4v){0,0,0,0},          \
                                                0,1,2,3,4,5,6,7);              \
            _Pragma("unroll")                                                  \
            for (int ni = 0; ni < 4; ++ni)                                     \
                acc[mi][ni] = __builtin_amdgcn_mfma_scale_f32_16x16x128_f8f6f4( \
                    afr, bfr[ni], acc[mi][ni], 4, 4,                           \
                    0, 0x7F7F7F7Fu, 0, 0x7F7F7F7Fu);                           \
        }                                                                      \
        __builtin_amdgcn_s_setprio(0);                                         \
    } while (0)

#define FENCE() asm volatile("" ::: "memory")
#define BAR()   do { FENCE(); __builtin_amdgcn_s_barrier(); FENCE(); } while (0)
#define VMW3()  asm volatile("s_waitcnt vmcnt(3)" ::: "memory")
#define VMW0()  asm volatile("s_waitcnt vmcnt(0)" ::: "memory")

    // prologue: stage tiles 0,1; retire tile 0 (VMW3 leaves tile 1's 3 in flight)
    STAGE(0, 0);
    STAGE(1, BKB);
    VMW3();
    BAR();

    #pragma unroll
    for (int kt = 0; kt < NKT; ++kt) {
        if (kt < NKT - 2) STAGE((kt + 2) % 3, (kt + 2) * BKB);
        COMPUTE(kt % 3);
        if (kt < NKT - 2)      { VMW3(); BAR(); }   // retire tile kt+1
        else if (kt == NKT - 2){ VMW0(); BAR(); }   // tail: tile kt+1 fully in
    }

    // -------- epilogue (C/D: col=lane&15, row=(lane>>4)*4+reg) --------
    const int il = wrow*64 + ((lane >> 4) << 2);  // + mi*16 + r
    const int jl = wcol*64 + (lane & 15);         // + ni*16

    float tbv[4];
    #pragma unroll
    for (int ni = 0; ni < 4; ++ni)
        tbv[ni] = TB[jrow0 + jl + ni*16];

    float pos = 0.f, neg = 0.f, cross = 0.f, cnt = 0.f;
    float mn = 1e30f;                        // min over valid neg/cross cands

    if (jj) {
        int labj[4];
        #pragma unroll
        for (int ni = 0; ni < 4; ++ni)
            labj[ni] = labels[tjc + jl + ni*16];
        const bool fullup = (tj >= 2*ti + 2);    // tile strictly above diagonal
        #pragma unroll
        for (int mi = 0; mi < 4; ++mi) {
            float4 sx4 = *(const float4*)&SXa[i0 + il + mi*16];
            int4   la4 = *(const int4*)&labels[i0 + il + mi*16];
            float sxr[4] = {sx4.x, sx4.y, sx4.z, sx4.w};
            int   lar[4] = {la4.x, la4.y, la4.z, la4.w};
            #pragma unroll
            for (int ni = 0; ni < 4; ++ni)
                #pragma unroll
                for (int r = 0; r < 4; ++r) {
                    float d2 = __builtin_fmaf(-2.f, acc[mi][ni][r],
                                              sxr[r] + tbv[ni]);
                    bool lt   = fullup | ((i0 + il + mi*16 + r) < (tjc + jl + ni*16));
                    bool same = (lar[r] == labj[ni]);
                    if (lt & same) { pos += fmaxf(d2, 0.f); cnt += 1.f; }
                    mn = fminf(mn, (lt & !same) ? d2 : 1e30f);
                }
        }
    } else {
        #pragma unroll
        for (int mi = 0; mi < 4; ++mi) {
            float4 sx4 = *(const float4*)&SXa[i0 + il + mi*16];
            float sxr[4] = {sx4.x, sx4.y, sx4.z, sx4.w};
            #pragma unroll
            for (int ni = 0; ni < 4; ++ni)
                #pragma unroll
                for (int r = 0; r < 4; ++r) {
                    float d2 = __builtin_fmaf(-2.f, acc[mi][ni][r],
                                              sxr[r] + tbv[ni]);
                    mn = fminf(mn, d2);
                }
        }
    }

    // rare exact path: only if some margin-active pair exists (never on this data)
    if (__any(mn < 1.f)) {
        int labj[4] = {0,0,0,0};
        if (jj)
            #pragma unroll
            for (int ni = 0; ni < 4; ++ni)
                labj[ni] = labels[tjc + jl + ni*16];
        const bool fullup = jj && (tj >= 2*ti + 2);
        #pragma unroll
        for (int mi = 0; mi < 4; ++mi) {
            float4 sx4 = *(const float4*)&SXa[i0 + il + mi*16];
            float sxr[4] = {sx4.x, sx4.y, sx4.z, sx4.w};
            int lar[4] = {0,0,0,0};
            if (jj) {
                int4 la4 = *(const int4*)&labels[i0 + il + mi*16];
                lar[0]=la4.x; lar[1]=la4.y; lar[2]=la4.z; lar[3]=la4.w;
            }
            #pragma unroll
            for (int ni = 0; ni < 4; ++ni)
                #pragma unroll
                for (int r = 0; r < 4; ++r) {
                    float d2 = __builtin_fmaf(-2.f, acc[mi][ni][r],
                                              sxr[r] + tbv[ni]);
                    d2 = fmaxf(d2, 0.f);
                    float dist = sqrtf(fmaxf(d2, 1e-12f));
                    float m = fmaxf(1.f - dist, 0.f);
                    float s2 = m * m;
                    if (jj) {
                        bool lt   = fullup | ((i0 + il + mi*16 + r) < (tjc + jl + ni*16));
                        bool same = (lar[r] == labj[ni]);
                        if (lt & !same) neg += s2;
                    } else {
                        cross += s2;
                    }
                }
        }
    }

    #pragma unroll
    for (int o = 32; o; o >>= 1) {
        pos   += __shfl_down(pos, o);
        neg   += __shfl_down(neg, o);
        cross += __shfl_down(cross, o);
        cnt   += __shfl_down(cnt, o);
    }
    if (lane == 0) { red[wave][0] = pos; red[wave][1] = neg;
                     red[wave][2] = cross; red[wave][3] = cnt; }
    __syncthreads();
    if (t == 0) {
        float4 v = {0.f, 0.f, 0.f, 0.f};
        #pragma unroll
        for (int w = 0; w < 8; ++w) {
            v.x += red[w][0]; v.y += red[w][1];
            v.z += red[w][2]; v.w += red[w][3];
        }
        partials[bid] = v;
    }
#undef STAGE
#undef COMPUTE
#undef FENCE
#undef BAR
#undef VMW3
#undef VMW0
}

// ---------------- final reduce ----------------
__global__ __launch_bounds__(256)
void finalize_kernel(const float4* __restrict__ partials, float* __restrict__ out) {
    int t = threadIdx.x;
    double p = 0, n = 0, c = 0, k = 0;
    for (int s = t; s < NBLK; s += 256) {
        float4 v = partials[s];
        p += v.x; n += v.y; c += v.z; k += v.w;
    }
    __shared__ double sh[256][4];
    sh[t][0] = p; sh[t][1] = n; sh[t][2] = c; sh[t][3] = k;
    __syncthreads();
    for (int o = 128; o; o >>= 1) {
        if (t < o) {
            sh[t][0] += sh[t+o][0]; sh[t][1] += sh[t+o][1];
            sh[t][2] += sh[t+o][2]; sh[t][3] += sh[t+o][3];
        }
        __syncthreads();
    }
    if (t == 0) {
        double npos = sh[0][3] < 1.0 ? 1.0 : sh[0][3];
        double total = (double)NROWS * (NROWS - 1) * 0.5;
        double nneg = total - sh[0][3]; if (nneg < 1.0) nneg = 1.0;
        double loss = sh[0][0] / npos + sh[0][1] / nneg
                    + sh[0][2] / ((double)NROWS * (double)NROWS);
        out[0] = (float)loss;
    }
}

extern "C" void kernel_launch(void* const* d_in, const int* in_sizes, int n_in,
                              void* d_out, int out_size, void* d_ws, size_t ws_size,
                              hipStream_t stream) {
    const float* X      = (const float*)d_in[0];
    const float* Y      = (const float*)d_in[1];
    const int*   labels = (const int*)d_in[2];
    float* out = (float*)d_out;
    char*  ws  = (char*)d_ws;

    // ws: partials (128KB) | SXa (32KB) | TB (64KB) | Zf4 (16384*384 = 6.3MB)
    float4* partials = (float4*)ws;
    float*  SXa      = (float*)(ws + 128*1024);
    float*  TB       = (float*)(ws + 128*1024 + 32*1024);
    uchar*  Zf4      = (uchar*)(ws + 256*1024);

    prep<<<2 * NROWS, 256, 0, stream>>>(X, Y, SXa, TB, Zf4);
    gemm_loss<<<NBLK, 512, 0, stream>>>(Zf4, labels, SXa, TB, partials);
    finalize_kernel<<<1, 256, 0, stream>>>(partials, out);
}

// Round 13
// 93.403 us; speedup vs baseline: 11.6008x; 1.0612x over previous
//
#include <hip/hip_runtime.h>
#include <hip/hip_bf16.h>
#include <stdint.h>
#include <math.h>

#define NROWS  8192
#define DIM    768                        // elements per row
#define DIMB   384                        // bytes per row in fp4 (4 bits/elem)
#define BKB    64                         // K-tile bytes (128 elements)
#define NKT    6                          // 768 / 128
#define BM     256
#define BN     128
#define EPSV   1e-6f
#define NTI    32                         // 8192/BM
#define NTJ    64                         // 8192/BN
#define NJN    (NTI * NTJ)                // 2048 X-vs-Y tiles
#define NJJ    1056                       // JJ tiles: sum_{ti}(64-2ti)
#define NBLK   (NJN + NJJ)                // 3104 = 8 * 388 (XCD-divisible)

typedef __attribute__((ext_vector_type(4))) int   int4v;
typedef __attribute__((ext_vector_type(8))) int   int8v;
typedef __attribute__((ext_vector_type(4))) float f32x4;
typedef unsigned char uchar;

// async global->LDS, 16B per lane; LDS dest is wave-uniform base (+lane*16 by HW)
__device__ __forceinline__ void gload16(const void* g, void* l) {
    __builtin_amdgcn_global_load_lds(
        (const __attribute__((address_space(1))) void*)g,
        (__attribute__((address_space(3))) void*)l,
        16, 0, 0);
}

// fp32 -> fp4 e2m1 nibble, round-to-nearest. Levels {0,.5,1,1.5,2,3,4,6}.
__device__ __forceinline__ uint32_t f2fp4(float x) {
    float a = fabsf(x);
    uint32_t c;
    if (a < 1.25f)      c = a < 0.25f ? 0u : (a < 0.75f ? 1u : 2u);
    else if (a < 2.5f)  c = a < 1.75f ? 3u : 4u;
    else                c = a < 3.5f ? 5u : (a < 5.0f ? 6u : 7u);
    return c | (x < 0.f ? 8u : 0u);
}

// ------- prep: fp4-e2m1 convert into Z=[X;Y], folded row stats (exact fp32) -------
// 2 rows per block: threads [0,128) = row 2*bid, [128,256) = row 2*bid+1;
// within a team, tt<96 active (75% lanes; r12 had 37.5%). Grid = 8192.
__global__ __launch_bounds__(256)
void prep(const float* __restrict__ X, const float* __restrict__ Y,
          float* __restrict__ SXa, float* __restrict__ TB,
          uchar* __restrict__ Zf4) {
    const int row = 2 * blockIdx.x + (threadIdx.x >> 7);   // 0..16383
    const int tt  = threadIdx.x & 127;
    const bool isX = row < NROWS;
    const float* p = (isX ? X : Y) + (size_t)(isX ? row : row - NROWS) * DIM;
    uint32_t* q = (uint32_t*)(Zf4 + (size_t)row * DIMB);
    float s = 0.f, qs = 0.f;
    if (tt < 96) {                         // 96 * 8 = 768 elems
        float4 v0 = *(const float4*)(p + 8 * tt);
        float4 v1 = *(const float4*)(p + 8 * tt + 4);
        uint32_t u = f2fp4(v0.x)        | (f2fp4(v0.y) << 4)  |
                     (f2fp4(v0.z) << 8) | (f2fp4(v0.w) << 12) |
                     (f2fp4(v1.x) << 16)| (f2fp4(v1.y) << 20) |
                     (f2fp4(v1.z) << 24)| (f2fp4(v1.w) << 28);
        q[tt] = u;
        s  = v0.x+v0.y+v0.z+v0.w + v1.x+v1.y+v1.z+v1.w;
        qs = v0.x*v0.x+v0.y*v0.y+v0.z*v0.z+v0.w*v0.w
           + v1.x*v1.x+v1.y*v1.y+v1.z*v1.z+v1.w*v1.w;
    }
    #pragma unroll
    for (int o = 32; o; o >>= 1) { s += __shfl_down(s, o); qs += __shfl_down(qs, o); }
    __shared__ float sh[8];
    const int wave = threadIdx.x >> 6, lane = threadIdx.x & 63;
    if (lane == 0) { sh[wave] = s; sh[4 + wave] = qs; }
    __syncthreads();
    if (tt == 0) {                          // thread 0 (row even) and 128 (row odd)
        const int w0 = (threadIdx.x >> 7) * 2;
        float ss = sh[w0] + sh[w0 + 1];
        float qq = sh[4 + w0] + sh[4 + w0 + 1];
        if (isX) SXa[row] = qq + 2.f*EPSV*ss;
        TB[row] = qq - 2.f*EPSV*ss + (float)DIM*EPSV*EPSV;
    }
}

// ------- fused MX-fp4 GEMM, 256x128 tile, 8 waves (4Mx2N), 3-deep pipeline -------
// (unchanged from r12: 73 us, MfmaUtil 21%, zero spill, 2 blocks/CU)
// LDS swizzle (involution, 64B rows): LDS byte (row, c) holds global byte
// c ^ ((row&3)<<4); linear gload_lds dest + pre-swizzled global source; ds_read
// applies the same XOR.
// Register budget: acc 4x4 f32x4 = 64 AGPR + 60 VGPR = 124 <= 128 cap at
// 2 blocks/CU (launch_bounds(512,4)). Do NOT add live state across barriers.
__global__ __launch_bounds__(512, 4)
void gemm_loss(const uchar* __restrict__ Z, const int* __restrict__ labels,
               const float* __restrict__ SXa, const float* __restrict__ TB,
               float4* __restrict__ partials) {
    // bijective XCD swizzle: 3104 = 8 * 388
    const int bid = (blockIdx.x & 7) * (NBLK / 8) + (blockIdx.x >> 3);
    const int t = threadIdx.x;

    int ti, tj, jrow0;                      // jrow0 = B-side row base in Z
    bool jj;
    if (bid < NJN) {
        jj = false; ti = bid >> 6; tj = bid & 63; jrow0 = NROWS + tj * BN;
    } else {
        jj = true;
        int u = bid - NJN;                  // 0..1055; row ti has 64-2ti entries
        int t0 = (int)((65.0 - sqrt(65.0*65.0 - 4.0*(double)u)) * 0.5);
        if (t0 < 0) t0 = 0; if (t0 > 31) t0 = 31;
        while (t0 < 31 && (t0 + 1) * (65 - (t0 + 1)) <= u) ++t0;
        while (t0 > 0  && t0 * (65 - t0) > u) --t0;
        ti = t0; tj = 2*ti + (u - ti * (65 - ti)); jrow0 = tj * BN;
    }
    const int i0 = ti * BM;
    const int tjc = tj * BN;                // B-side column base (labels/lt)

    __shared__ __align__(16) uchar Asm[3][BM * BKB];   // 16 KB per buf
    __shared__ __align__(16) uchar Bsm[3][BN * BKB];   // 8 KB per buf
    __shared__ float red[8][4];

    const int wave = t >> 6, lane = t & 63;
    const int wrow = wave >> 1;             // 0..3 (M quarter: 64 rows)
    const int wcol = wave & 1;              // 0..1 (N half: 64 cols)

    // staging: chunk = 16 rows x 64B = 1KB; lane l -> row +(l>>2), slot l&3;
    // inverse-swizzled global col bytes:
    const int cS = ((lane & 3) * 16) ^ (((lane >> 2) & 3) << 4);
    const uchar* pAs = Z + (size_t)(i0 + 16*wave + (lane >> 2))    * DIMB + cS;
    const uchar* pBs = Z + (size_t)(jrow0 + 16*wave + (lane >> 2)) * DIMB + cS;

    const int lrow = lane & 15;
    const int kc   = (lane >> 4) * 16;      // 16-byte K-slot per lane quarter

    f32x4 acc[4][4] = {};

#define STAGE(b, kb)                                                           \
    do {                                                                       \
        gload16(pAs + (kb), &Asm[b][wave * 1024]);                             \
        gload16(pAs + (size_t)128 * DIMB + (kb), &Asm[b][(wave + 8) * 1024]);  \
        gload16(pBs + (kb), &Bsm[b][wave * 1024]);                             \
    } while (0)

#define COMPUTE(b)                                                             \
    do {                                                                       \
        int8v bfr[4];                                                          \
        _Pragma("unroll")                                                      \
        for (int ni = 0; ni < 4; ++ni) {                                       \
            int rr = wcol*64 + ni*16 + lrow;                                   \
            int4v lo = *(const int4v*)&Bsm[b][rr*64 + (kc ^ ((rr & 3) << 4))]; \
            bfr[ni] = __builtin_shufflevector(lo, (int4v){0,0,0,0},            \
                                              0,1,2,3,4,5,6,7);                \
        }                                                                      \
        __builtin_amdgcn_s_setprio(1);                                         \
        _Pragma("unroll")                                                      \
        for (int mi = 0; mi < 4; ++mi) {                                       \
            int rr = wrow*64 + mi*16 + lrow;                                   \
            int4v lo = *(const int4v*)&Asm[b][rr*64 + (kc ^ ((rr & 3) << 4))]; \
            int8v afr = __builtin_shufflevector(lo, (int4v){0,0,0,0},          \
                                                0,1,2,3,4,5,6,7);              \
            _Pragma("unroll")                                                  \
            for (int ni = 0; ni < 4; ++ni)                                     \
                acc[mi][ni] = __builtin_amdgcn_mfma_scale_f32_16x16x128_f8f6f4( \
                    afr, bfr[ni], acc[mi][ni], 4, 4,                           \
                    0, 0x7F7F7F7Fu, 0, 0x7F7F7F7Fu);                           \
        }                                                                      \
        __builtin_amdgcn_s_setprio(0);                                         \
    } while (0)

#define FENCE() asm volatile("" ::: "memory")
#define BAR()   do { FENCE(); __builtin_amdgcn_s_barrier(); FENCE(); } while (0)
#define VMW3()  asm volatile("s_waitcnt vmcnt(3)" ::: "memory")
#define VMW0()  asm volatile("s_waitcnt vmcnt(0)" ::: "memory")

    // prologue: stage tiles 0,1; retire tile 0 (VMW3 leaves tile 1's 3 in flight)
    STAGE(0, 0);
    STAGE(1, BKB);
    VMW3();
    BAR();

    #pragma unroll
    for (int kt = 0; kt < NKT; ++kt) {
        if (kt < NKT - 2) STAGE((kt + 2) % 3, (kt + 2) * BKB);
        COMPUTE(kt % 3);
        if (kt < NKT - 2)      { VMW3(); BAR(); }   // retire tile kt+1
        else if (kt == NKT - 2){ VMW0(); BAR(); }   // tail: tile kt+1 fully in
    }

    // -------- epilogue (C/D: col=lane&15, row=(lane>>4)*4+reg) --------
    const int il = wrow*64 + ((lane >> 4) << 2);  // + mi*16 + r
    const int jl = wcol*64 + (lane & 15);         // + ni*16

    float tbv[4];
    #pragma unroll
    for (int ni = 0; ni < 4; ++ni)
        tbv[ni] = TB[jrow0 + jl + ni*16];

    float pos = 0.f, neg = 0.f, cross = 0.f, cnt = 0.f;
    float mn = 1e30f;                        // min over valid neg/cross cands

    if (jj) {
        int labj[4];
        #pragma unroll
        for (int ni = 0; ni < 4; ++ni)
            labj[ni] = labels[tjc + jl + ni*16];
        const bool fullup = (tj >= 2*ti + 2);    // tile strictly above diagonal
        #pragma unroll
        for (int mi = 0; mi < 4; ++mi) {
            float4 sx4 = *(const float4*)&SXa[i0 + il + mi*16];
            int4   la4 = *(const int4*)&labels[i0 + il + mi*16];
            float sxr[4] = {sx4.x, sx4.y, sx4.z, sx4.w};
            int   lar[4] = {la4.x, la4.y, la4.z, la4.w};
            #pragma unroll
            for (int ni = 0; ni < 4; ++ni)
                #pragma unroll
                for (int r = 0; r < 4; ++r) {
                    float d2 = __builtin_fmaf(-2.f, acc[mi][ni][r],
                                              sxr[r] + tbv[ni]);
                    bool lt   = fullup | ((i0 + il + mi*16 + r) < (tjc + jl + ni*16));
                    bool same = (lar[r] == labj[ni]);
                    if (lt & same) { pos += fmaxf(d2, 0.f); cnt += 1.f; }
                    mn = fminf(mn, (lt & !same) ? d2 : 1e30f);
                }
        }
    } else {
        #pragma unroll
        for (int mi = 0; mi < 4; ++mi) {
            float4 sx4 = *(const float4*)&SXa[i0 + il + mi*16];
            float sxr[4] = {sx4.x, sx4.y, sx4.z, sx4.w};
            #pragma unroll
            for (int ni = 0; ni < 4; ++ni)
                #pragma unroll
                for (int r = 0; r < 4; ++r) {
                    float d2 = __builtin_fmaf(-2.f, acc[mi][ni][r],
                                              sxr[r] + tbv[ni]);
                    mn = fminf(mn, d2);
                }
        }
    }

    // rare exact path: only if some margin-active pair exists (never on this data)
    if (__any(mn < 1.f)) {
        int labj[4] = {0,0,0,0};
        if (jj)
            #pragma unroll
            for (int ni = 0; ni < 4; ++ni)
                labj[ni] = labels[tjc + jl + ni*16];
        const bool fullup = jj && (tj >= 2*ti + 2);
        #pragma unroll
        for (int mi = 0; mi < 4; ++mi) {
            float4 sx4 = *(const float4*)&SXa[i0 + il + mi*16];
            float sxr[4] = {sx4.x, sx4.y, sx4.z, sx4.w};
            int lar[4] = {0,0,0,0};
            if (jj) {
                int4 la4 = *(const int4*)&labels[i0 + il + mi*16];
                lar[0]=la4.x; lar[1]=la4.y; lar[2]=la4.z; lar[3]=la4.w;
            }
            #pragma unroll
            for (int ni = 0; ni < 4; ++ni)
                #pragma unroll
                for (int r = 0; r < 4; ++r) {
                    float d2 = __builtin_fmaf(-2.f, acc[mi][ni][r],
                                              sxr[r] + tbv[ni]);
                    d2 = fmaxf(d2, 0.f);
                    float dist = sqrtf(fmaxf(d2, 1e-12f));
                    float m = fmaxf(1.f - dist, 0.f);
                    float s2 = m * m;
                    if (jj) {
                        bool lt   = fullup | ((i0 + il + mi*16 + r) < (tjc + jl + ni*16));
                        bool same = (lar[r] == labj[ni]);
                        if (lt & !same) neg += s2;
                    } else {
                        cross += s2;
                    }
                }
        }
    }

    #pragma unroll
    for (int o = 32; o; o >>= 1) {
        pos   += __shfl_down(pos, o);
        neg   += __shfl_down(neg, o);
        cross += __shfl_down(cross, o);
        cnt   += __shfl_down(cnt, o);
    }
    if (lane == 0) { red[wave][0] = pos; red[wave][1] = neg;
                     red[wave][2] = cross; red[wave][3] = cnt; }
    __syncthreads();
    if (t == 0) {
        float4 v = {0.f, 0.f, 0.f, 0.f};
        #pragma unroll
        for (int w = 0; w < 8; ++w) {
            v.x += red[w][0]; v.y += red[w][1];
            v.z += red[w][2]; v.w += red[w][3];
        }
        partials[bid] = v;
    }
#undef STAGE
#undef COMPUTE
#undef FENCE
#undef BAR
#undef VMW3
#undef VMW0
}

// ---------------- final reduce ----------------
__global__ __launch_bounds__(256)
void finalize_kernel(const float4* __restrict__ partials, float* __restrict__ out) {
    int t = threadIdx.x;
    double p = 0, n = 0, c = 0, k = 0;
    for (int s = t; s < NBLK; s += 256) {
        float4 v = partials[s];
        p += v.x; n += v.y; c += v.z; k += v.w;
    }
    __shared__ double sh[256][4];
    sh[t][0] = p; sh[t][1] = n; sh[t][2] = c; sh[t][3] = k;
    __syncthreads();
    for (int o = 128; o; o >>= 1) {
        if (t < o) {
            sh[t][0] += sh[t+o][0]; sh[t][1] += sh[t+o][1];
            sh[t][2] += sh[t+o][2]; sh[t][3] += sh[t+o][3];
        }
        __syncthreads();
    }
    if (t == 0) {
        double npos = sh[0][3] < 1.0 ? 1.0 : sh[0][3];
        double total = (double)NROWS * (NROWS - 1) * 0.5;
        double nneg = total - sh[0][3]; if (nneg < 1.0) nneg = 1.0;
        double loss = sh[0][0] / npos + sh[0][1] / nneg
                    + sh[0][2] / ((double)NROWS * (double)NROWS);
        out[0] = (float)loss;
    }
}

extern "C" void kernel_launch(void* const* d_in, const int* in_sizes, int n_in,
                              void* d_out, int out_size, void* d_ws, size_t ws_size,
                              hipStream_t stream) {
    const float* X      = (const float*)d_in[0];
    const float* Y      = (const float*)d_in[1];
    const int*   labels = (const int*)d_in[2];
    float* out = (float*)d_out;
    char*  ws  = (char*)d_ws;

    // ws: partials (128KB) | SXa (32KB) | TB (64KB) | Zf4 (16384*384 = 6.3MB)
    float4* partials = (float4*)ws;
    float*  SXa      = (float*)(ws + 128*1024);
    float*  TB       = (float*)(ws + 128*1024 + 32*1024);
    uchar*  Zf4      = (uchar*)(ws + 256*1024);

    prep<<<NROWS, 256, 0, stream>>>(X, Y, SXa, TB, Zf4);
    gemm_loss<<<NBLK, 512, 0, stream>>>(Zf4, labels, SXa, TB, partials);
    finalize_kernel<<<1, 256, 0, stream>>>(partials, out);
}